// Round 1
// baseline (10862.894 us; speedup 1.0000x reference)
//
#include <hip/hip_runtime.h>
#include <cstdint>
#include <cstddef>

// ---------------- dims ----------------
#define BATCH 2
#define MQ 12544          // B * TQ * NQ = 2*32*196
#define ROWS_Q 6272       // TQ*NQ per sample
#define MK 4096           // B * T*H*W = 2*2048
#define ROWS_K 2048       // kv tokens per sample
#define HID 512
#define NH 4
#define HD 128
#define EMB 1024
#define DQ 896
#define FF 1024
#define OUTD 896

#define BM 64
#define BN 64
#define BK 16

enum { OP_BIAS = 0, OP_GELU = 1, OP_RES = 2 };

__device__ __forceinline__ float gelu_tanh(float x) {
    float x3 = x * x * x;
    return 0.5f * x * (1.0f + tanhf(0.7978845608028654f * (x + 0.044715f * x3)));
}

// Generic fp32 tiled GEMM: C = A(MxK) @ B(KxN) + bias, epilogue op.
// M, N must be multiples of 64; K arbitrary (guarded).
template <int OP>
__global__ __launch_bounds__(256) void gemm_kernel(
    const float* __restrict__ A, const float* __restrict__ B,
    const float* __restrict__ bias, const float* __restrict__ res,
    float* __restrict__ C, int M, int N, int K)
{
    __shared__ float As[BM][BK + 1];   // +1 pad: conflict-free stores, scalar reads ok
    __shared__ float Bs[BK][BN];
    const int tid = threadIdx.x;
    const int bm0 = blockIdx.y * BM;
    const int bn0 = blockIdx.x * BN;
    const int tx = tid & 15;   // n-dir, 16 threads
    const int ty = tid >> 4;   // m-dir, 16 threads
    float acc[4][4] = {};

    for (int k0 = 0; k0 < K; k0 += BK) {
        #pragma unroll
        for (int i = 0; i < 4; ++i) {
            int l = tid + i * 256;
            int r = l >> 4, c = l & 15;          // A tile: 64 rows x 16 k
            As[r][c] = (k0 + c < K) ? A[(size_t)(bm0 + r) * K + k0 + c] : 0.0f;
            int rb = l >> 6, cb = l & 63;        // B tile: 16 k x 64 cols
            Bs[rb][cb] = (k0 + rb < K) ? B[(size_t)(k0 + rb) * N + bn0 + cb] : 0.0f;
        }
        __syncthreads();
        #pragma unroll
        for (int kk = 0; kk < BK; ++kk) {
            float a[4], b[4];
            #pragma unroll
            for (int i = 0; i < 4; ++i) a[i] = As[ty * 4 + i][kk];
            #pragma unroll
            for (int j = 0; j < 4; ++j) b[j] = Bs[kk][tx * 4 + j];
            #pragma unroll
            for (int i = 0; i < 4; ++i)
                #pragma unroll
                for (int j = 0; j < 4; ++j)
                    acc[i][j] = fmaf(a[i], b[j], acc[i][j]);
        }
        __syncthreads();
    }

    #pragma unroll
    for (int i = 0; i < 4; ++i) {
        int m = bm0 + ty * 4 + i;
        #pragma unroll
        for (int j = 0; j < 4; ++j) {
            int n = bn0 + tx * 4 + j;
            float v = acc[i][j] + bias[n];
            if (OP == OP_GELU) v = gelu_tanh(v);
            if (OP == OP_RES)  v += res[(size_t)m * N + n];
            C[(size_t)m * N + n] = v;
        }
    }
}

// 3D RoPE in-place on a (rows x 512) buffer viewed as (rows, 4 heads, 128).
// One thread per (row, head, freq j<64): rotates pair (j, j+64).
__global__ __launch_bounds__(256) void rope_kernel(
    float* __restrict__ buf, int tok, int gdiv, int wdiv, int total)
{
    int idx = blockIdx.x * 256 + threadIdx.x;
    if (idx >= total) return;
    int row = idx >> 8;
    int r2 = idx & 255;
    int h = r2 >> 6;
    int j = r2 & 63;
    int n = row % tok;          // token index within sample
    int t = n / gdiv;
    int g = n % gdiv;
    int gh = g / wdiv;
    int gw = g % wdiv;
    float p = (j < 22) ? (float)t : (j < 43) ? (float)gh : (float)gw;
    // inv_freq = 10000^(-j/64) = 2^(-j*log2(1e4)/64)
    float inv_freq = exp2f(-(float)j * 0.20762050593045954f);
    float fr = p * inv_freq;
    float c = cosf(fr), s = sinf(fr);
    size_t base = (size_t)row * 512 + (size_t)h * 128 + j;
    float x1 = buf[base], x2 = buf[base + 64];
    buf[base]      = x1 * c - x2 * s;
    buf[base + 64] = x2 * c + x1 * s;
}

// LayerNorm in-place on (rows x 512). One wave per row.
__global__ __launch_bounds__(256) void ln_kernel(
    float* __restrict__ xb, const float* __restrict__ g, const float* __restrict__ be)
{
    int wave = threadIdx.x >> 6, lane = threadIdx.x & 63;
    size_t row = (size_t)blockIdx.x * 4 + wave;
    float* xp = xb + row * 512;
    float4 a = ((const float4*)xp)[lane];
    float4 b = ((const float4*)xp)[lane + 64];
    float s  = a.x + a.y + a.z + a.w + b.x + b.y + b.z + b.w;
    float sq = a.x*a.x + a.y*a.y + a.z*a.z + a.w*a.w
             + b.x*b.x + b.y*b.y + b.z*b.z + b.w*b.w;
    #pragma unroll
    for (int off = 32; off; off >>= 1) {
        s  += __shfl_xor(s, off);
        sq += __shfl_xor(sq, off);
    }
    float mean = s * (1.0f / 512.0f);
    float var  = sq * (1.0f / 512.0f) - mean * mean;
    float rstd = rsqrtf(var + 1e-5f);
    float4 gv1 = ((const float4*)g)[lane],  gv2 = ((const float4*)g)[lane + 64];
    float4 bv1 = ((const float4*)be)[lane], bv2 = ((const float4*)be)[lane + 64];
    a.x = (a.x - mean) * rstd * gv1.x + bv1.x;
    a.y = (a.y - mean) * rstd * gv1.y + bv1.y;
    a.z = (a.z - mean) * rstd * gv1.z + bv1.z;
    a.w = (a.w - mean) * rstd * gv1.w + bv1.w;
    b.x = (b.x - mean) * rstd * gv2.x + bv2.x;
    b.y = (b.y - mean) * rstd * gv2.y + bv2.y;
    b.z = (b.z - mean) * rstd * gv2.z + bv2.z;
    b.w = (b.w - mean) * rstd * gv2.w + bv2.w;
    ((float4*)xp)[lane]      = a;
    ((float4*)xp)[lane + 64] = b;
}

// Cross-attention, one wave per (b, head, q-row); writes output in-place over q.
// q: (B*6272, 512) head-interleaved; k,v: (B*2048, 512).
__global__ __launch_bounds__(256) void attn_kernel(
    float* __restrict__ q, const float* __restrict__ k, const float* __restrict__ v)
{
    __shared__ float logits[4][2048];
    __shared__ float qsh[4][128];
    const int wave = threadIdx.x >> 6, lane = threadIdx.x & 63;
    const int row = blockIdx.x * 4 + wave;          // < B*NH*6272 = 50176
    const int b   = row / (NH * ROWS_Q);
    const int rem = row % (NH * ROWS_Q);
    const int h   = rem / ROWS_Q;
    const int qi  = rem % ROWS_Q;
    float* qp = q + ((size_t)(b * ROWS_Q + qi)) * HID + h * HD;
    const float* kbase = k + ((size_t)(b * ROWS_K)) * HID + h * HD;
    const float* vbase = v + ((size_t)(b * ROWS_K)) * HID + h * HD;

    // load this row's q fragment into LDS
    ((float2*)qsh[wave])[lane] = ((const float2*)qp)[lane];
    __syncthreads();

    // pass 1: logits
    float lmax = -1e30f;
    for (int kb = lane; kb < ROWS_K; kb += 64) {
        const float* kp = kbase + (size_t)kb * HID;
        float dot = 0.0f;
        #pragma unroll
        for (int d = 0; d < HD; d += 4) {
            float4 kv4 = *(const float4*)(kp + d);
            dot = fmaf(qsh[wave][d],     kv4.x, dot);
            dot = fmaf(qsh[wave][d + 1], kv4.y, dot);
            dot = fmaf(qsh[wave][d + 2], kv4.z, dot);
            dot = fmaf(qsh[wave][d + 3], kv4.w, dot);
        }
        dot *= 0.08838834764831843f;   // 1/sqrt(128)
        logits[wave][kb] = dot;
        lmax = fmaxf(lmax, dot);
    }
    #pragma unroll
    for (int off = 32; off; off >>= 1) lmax = fmaxf(lmax, __shfl_xor(lmax, off));

    float lsum = 0.0f;
    for (int kb = lane; kb < ROWS_K; kb += 64) {
        float p = expf(logits[wave][kb] - lmax);
        logits[wave][kb] = p;
        lsum += p;
    }
    #pragma unroll
    for (int off = 32; off; off >>= 1) lsum += __shfl_xor(lsum, off);
    float inv = 1.0f / lsum;
    __syncthreads();   // make all lanes' logits visible wave-wide

    // pass 2: O = P @ V; each lane owns 2 output dims
    const float* vp = vbase + lane * 2;
    float acc0 = 0.0f, acc1 = 0.0f;
    #pragma unroll 4
    for (int kb = 0; kb < ROWS_K; ++kb) {
        float p = logits[wave][kb];
        float2 vv = *(const float2*)(vp + (size_t)kb * HID);
        acc0 = fmaf(p, vv.x, acc0);
        acc1 = fmaf(p, vv.y, acc1);
    }
    ((float2*)qp)[lane] = make_float2(acc0 * inv, acc1 * inv);
}

extern "C" void kernel_launch(void* const* d_in, const int* in_sizes, int n_in,
                              void* d_out, int out_size, void* d_ws, size_t ws_size,
                              hipStream_t stream)
{
    const float* x     = (const float*)d_in[0];
    const float* slow  = (const float*)d_in[1];
    // d_in[2] frame_num: all samples full length, unused
    const float* Wq_in = (const float*)d_in[3];
    const float* bq_in = (const float*)d_in[4];
    const float* Wm    = (const float*)d_in[5];
    const float* bm    = (const float*)d_in[6];
    const float* Wq    = (const float*)d_in[7];
    const float* bq    = (const float*)d_in[8];
    const float* Wk    = (const float*)d_in[9];
    const float* bk    = (const float*)d_in[10];
    const float* Wv    = (const float*)d_in[11];
    const float* bv    = (const float*)d_in[12];
    const float* Wo    = (const float*)d_in[13];
    const float* bo    = (const float*)d_in[14];
    const float* g1    = (const float*)d_in[15];
    const float* be1   = (const float*)d_in[16];
    const float* W1    = (const float*)d_in[17];
    const float* b1    = (const float*)d_in[18];
    const float* W2    = (const float*)d_in[19];
    const float* b2    = (const float*)d_in[20];
    const float* g2    = (const float*)d_in[21];
    const float* be2   = (const float*)d_in[22];
    const float* M1    = (const float*)d_in[23];
    const float* bm1   = (const float*)d_in[24];
    const float* M2    = (const float*)d_in[25];
    const float* bm2   = (const float*)d_in[26];
    float* out = (float*)d_out;

    // workspace layout (fp32), ~162 MB total
    float* ws   = (float*)d_ws;
    float* q_in = ws;                              // 12544*512
    float* kv   = q_in + (size_t)MQ * HID;         // 4096*1024
    float* qb   = kv   + (size_t)MK * EMB;         // 12544*512 (q heads -> attn out in-place)
    float* kb   = qb   + (size_t)MQ * HID;         // 4096*512
    float* vb   = kb   + (size_t)MK * HID;         // 4096*512
    float* ob   = vb   + (size_t)MK * HID;         // 12544*512 (o+res -> h in-place)
    float* ffb  = ob   + (size_t)MQ * HID;         // 12544*1024 (ff1, later mlp1)

    dim3 blk(256);

    // 1. q_in = slow @ Wq_in + bq_in          (12544x896 @ 896x512)
    gemm_kernel<OP_BIAS><<<dim3(HID / BN, MQ / BM), blk, 0, stream>>>(
        slow, Wq_in, bq_in, nullptr, q_in, MQ, HID, DQ);
    // 2. kv = x @ Wm + bm                     (4096x4 @ 4x1024)
    gemm_kernel<OP_BIAS><<<dim3(EMB / BN, MK / BM), blk, 0, stream>>>(
        x, Wm, bm, nullptr, kv, MK, EMB, 4);
    // 3. q = q_in @ Wq + bq                   (12544x512 @ 512x512)
    gemm_kernel<OP_BIAS><<<dim3(HID / BN, MQ / BM), blk, 0, stream>>>(
        q_in, Wq, bq, nullptr, qb, MQ, HID, HID);
    // 4. k = kv @ Wk + bk                     (4096x1024 @ 1024x512)
    gemm_kernel<OP_BIAS><<<dim3(HID / BN, MK / BM), blk, 0, stream>>>(
        kv, Wk, bk, nullptr, kb, MK, HID, EMB);
    // 5. v = kv @ Wv + bv
    gemm_kernel<OP_BIAS><<<dim3(HID / BN, MK / BM), blk, 0, stream>>>(
        kv, Wv, bv, nullptr, vb, MK, HID, EMB);
    // 6/7. RoPE on q (grid 14x14, t=n/196) and k (grid 8x8, t=n/64)
    rope_kernel<<<MQ, blk, 0, stream>>>(qb, ROWS_Q, 196, 14, MQ * 256);
    rope_kernel<<<MK, blk, 0, stream>>>(kb, ROWS_K, 64, 8, MK * 256);
    // 8. attention (in-place into qb)
    attn_kernel<<<(BATCH * NH * ROWS_Q) / 4, blk, 0, stream>>>(qb, kb, vb);
    // 9. pre_ln = attn_out @ Wo + bo + q_in
    gemm_kernel<OP_RES><<<dim3(HID / BN, MQ / BM), blk, 0, stream>>>(
        qb, Wo, bo, q_in, ob, MQ, HID, HID);
    // 10. h = LN(pre_ln) (in-place)
    ln_kernel<<<MQ / 4, blk, 0, stream>>>(ob, g1, be1);
    // 11. ff1 = gelu(h @ W1 + b1)             (12544x512 @ 512x1024)
    gemm_kernel<OP_GELU><<<dim3(FF / BN, MQ / BM), blk, 0, stream>>>(
        ob, W1, b1, nullptr, ffb, MQ, FF, HID);
    // 12. pre2 = ff1 @ W2 + b2 + h            (into q_in, now free)
    gemm_kernel<OP_RES><<<dim3(HID / BN, MQ / BM), blk, 0, stream>>>(
        ffb, W2, b2, ob, q_in, MQ, HID, FF);
    // 13. h2 = LN(pre2) (in-place)
    ln_kernel<<<MQ / 4, blk, 0, stream>>>(q_in, g2, be2);
    // 14. m1 = gelu(h2 @ M1 + bm1)            (12544x512 @ 512x1024)
    gemm_kernel<OP_GELU><<<dim3((2 * HID) / BN, MQ / BM), blk, 0, stream>>>(
        q_in, M1, bm1, nullptr, ffb, MQ, 2 * HID, HID);
    // 15. out = m1 @ M2 + bm2                 (12544x1024 @ 1024x896)
    gemm_kernel<OP_BIAS><<<dim3(OUTD / BN, MQ / BM), blk, 0, stream>>>(
        ffb, M2, bm2, nullptr, out, MQ, OUTD, 2 * HID);
}

// Round 2
// 3675.278 us; speedup vs baseline: 2.9557x; 2.9557x over previous
//
#include <hip/hip_runtime.h>
#include <cstdint>
#include <cstddef>

// ---------------- dims ----------------
#define BATCH 2
#define MQ 12544          // B * TQ * NQ = 2*32*196
#define ROWS_Q 6272       // TQ*NQ per sample
#define MK 4096           // B * T*H*W = 2*2048
#define ROWS_K 2048       // kv tokens per sample
#define HID 512
#define NH 4
#define HD 128
#define EMB 1024
#define DQ 896
#define FF 1024
#define OUTD 896

#define BM 64
#define BN 64
#define BK 16

enum { OP_BIAS = 0, OP_GELU = 1, OP_RES = 2 };

__device__ __forceinline__ float gelu_tanh(float x) {
    float x3 = x * x * x;
    return 0.5f * x * (1.0f + tanhf(0.7978845608028654f * (x + 0.044715f * x3)));
}

// Generic fp32 tiled GEMM: C = A(MxK) @ B(KxN) + bias, epilogue op.
template <int OP>
__global__ __launch_bounds__(256) void gemm_kernel(
    const float* __restrict__ A, const float* __restrict__ B,
    const float* __restrict__ bias, const float* __restrict__ res,
    float* __restrict__ C, int M, int N, int K)
{
    __shared__ float As[BM][BK + 1];
    __shared__ float Bs[BK][BN];
    const int tid = threadIdx.x;
    const int bm0 = blockIdx.y * BM;
    const int bn0 = blockIdx.x * BN;
    const int tx = tid & 15;
    const int ty = tid >> 4;
    float acc[4][4] = {};

    for (int k0 = 0; k0 < K; k0 += BK) {
        #pragma unroll
        for (int i = 0; i < 4; ++i) {
            int l = tid + i * 256;
            int r = l >> 4, c = l & 15;
            As[r][c] = (k0 + c < K) ? A[(size_t)(bm0 + r) * K + k0 + c] : 0.0f;
            int rb = l >> 6, cb = l & 63;
            Bs[rb][cb] = (k0 + rb < K) ? B[(size_t)(k0 + rb) * N + bn0 + cb] : 0.0f;
        }
        __syncthreads();
        #pragma unroll
        for (int kk = 0; kk < BK; ++kk) {
            float a[4], b[4];
            #pragma unroll
            for (int i = 0; i < 4; ++i) a[i] = As[ty * 4 + i][kk];
            #pragma unroll
            for (int j = 0; j < 4; ++j) b[j] = Bs[kk][tx * 4 + j];
            #pragma unroll
            for (int i = 0; i < 4; ++i)
                #pragma unroll
                for (int j = 0; j < 4; ++j)
                    acc[i][j] = fmaf(a[i], b[j], acc[i][j]);
        }
        __syncthreads();
    }

    #pragma unroll
    for (int i = 0; i < 4; ++i) {
        int m = bm0 + ty * 4 + i;
        #pragma unroll
        for (int j = 0; j < 4; ++j) {
            int n = bn0 + tx * 4 + j;
            float v = acc[i][j] + bias[n];
            if (OP == OP_GELU) v = gelu_tanh(v);
            if (OP == OP_RES)  v += res[(size_t)m * N + n];
            C[(size_t)m * N + n] = v;
        }
    }
}

// 3D RoPE in-place on (rows x 512) viewed as (rows, 4 heads, 128).
__global__ __launch_bounds__(256) void rope_kernel(
    float* __restrict__ buf, int tok, int gdiv, int wdiv, int total)
{
    int idx = blockIdx.x * 256 + threadIdx.x;
    if (idx >= total) return;
    int row = idx >> 8;
    int r2 = idx & 255;
    int h = r2 >> 6;
    int j = r2 & 63;
    int n = row % tok;
    int t = n / gdiv;
    int g = n % gdiv;
    int gh = g / wdiv;
    int gw = g % wdiv;
    float p = (j < 22) ? (float)t : (j < 43) ? (float)gh : (float)gw;
    float inv_freq = exp2f(-(float)j * 0.20762050593045954f);
    float fr = p * inv_freq;
    float c = cosf(fr), s = sinf(fr);
    size_t base = (size_t)row * 512 + (size_t)h * 128 + j;
    float x1 = buf[base], x2 = buf[base + 64];
    buf[base]      = x1 * c - x2 * s;
    buf[base + 64] = x2 * c + x1 * s;
}

// LayerNorm in-place on (rows x 512). One wave per row.
__global__ __launch_bounds__(256) void ln_kernel(
    float* __restrict__ xb, const float* __restrict__ g, const float* __restrict__ be)
{
    int wave = threadIdx.x >> 6, lane = threadIdx.x & 63;
    size_t row = (size_t)blockIdx.x * 4 + wave;
    float* xp = xb + row * 512;
    float4 a = ((const float4*)xp)[lane];
    float4 b = ((const float4*)xp)[lane + 64];
    float s  = a.x + a.y + a.z + a.w + b.x + b.y + b.z + b.w;
    float sq = a.x*a.x + a.y*a.y + a.z*a.z + a.w*a.w
             + b.x*b.x + b.y*b.y + b.z*b.z + b.w*b.w;
    #pragma unroll
    for (int off = 32; off; off >>= 1) {
        s  += __shfl_xor(s, off);
        sq += __shfl_xor(sq, off);
    }
    float mean = s * (1.0f / 512.0f);
    float var  = sq * (1.0f / 512.0f) - mean * mean;
    float rstd = rsqrtf(var + 1e-5f);
    float4 gv1 = ((const float4*)g)[lane],  gv2 = ((const float4*)g)[lane + 64];
    float4 bv1 = ((const float4*)be)[lane], bv2 = ((const float4*)be)[lane + 64];
    a.x = (a.x - mean) * rstd * gv1.x + bv1.x;
    a.y = (a.y - mean) * rstd * gv1.y + bv1.y;
    a.z = (a.z - mean) * rstd * gv1.z + bv1.z;
    a.w = (a.w - mean) * rstd * gv1.w + bv1.w;
    b.x = (b.x - mean) * rstd * gv2.x + bv2.x;
    b.y = (b.y - mean) * rstd * gv2.y + bv2.y;
    b.z = (b.z - mean) * rstd * gv2.z + bv2.z;
    b.w = (b.w - mean) * rstd * gv2.w + bv2.w;
    ((float4*)xp)[lane]      = a;
    ((float4*)xp)[lane + 64] = b;
}

// ---------------------------------------------------------------------------
// Flash attention (fp32). One block per (b, head, 64-row q-tile).
// q (in/out): (B*6272, 512) head-interleaved. k, v: (B*2048, 512).
//
// LDS (exactly 64 KB -> 2 blocks/CU):
//   Qt[128][64]  : Q-tile transposed [d][r], col XOR-swizzled by 4*((d>>2)&15)
//   buf[8192]    : S-phase = Kt[128][64] (same swizzle)
//                  PV-phase = P[64][64] (col XOR 4*(r>>2)) | Vh[64][64]
// Thread grid 16(ty: 4 rows each) x 16(tx): S acc 4x4, O acc 4x8
// (cols = hh*64 + 4*tx + j).
// ---------------------------------------------------------------------------
__global__ __launch_bounds__(256, 2) void fattn_kernel(
    float* __restrict__ q, const float* __restrict__ k, const float* __restrict__ v)
{
    __shared__ float Qt[128 * 64];
    __shared__ float buf[8192];
    float* Pb = buf;
    float* Vb = buf + 4096;

    const int tid = threadIdx.x;
    const int tx = tid & 15, ty = tid >> 4;
    const int bid = blockIdx.x;
    const int qt = bid % 98;
    const int h  = (bid / 98) & 3;
    const int b  = bid / 392;

    float* qg       = q + ((size_t)(b * ROWS_Q + qt * 64)) * HID + h * HD;
    const float* kg = k + ((size_t)(b * ROWS_K)) * HID + h * HD;
    const float* vg = v + ((size_t)(b * ROWS_K)) * HID + h * HD;

    // ---- load Q tile transposed + swizzled ----
    {
        const int r0 = tid >> 5;           // 0..7
        const int c  = tid & 31;           // d0 = 4c
        const int s  = 4 * (c & 15);
        #pragma unroll
        for (int p = 0; p < 8; ++p) {
            int rr = r0 + 8 * p;
            float4 qv = *(const float4*)(qg + (size_t)rr * HID + 4 * c);
            Qt[(4 * c + 0) * 64 + (rr ^ s)] = qv.x;
            Qt[(4 * c + 1) * 64 + (rr ^ s)] = qv.y;
            Qt[(4 * c + 2) * 64 + (rr ^ s)] = qv.z;
            Qt[(4 * c + 3) * 64 + (rr ^ s)] = qv.w;
        }
    }

    float m_i[4], l_i[4], o[4][8];
    #pragma unroll
    for (int i = 0; i < 4; ++i) {
        m_i[i] = -1e30f; l_i[i] = 0.0f;
        #pragma unroll
        for (int j = 0; j < 8; ++j) o[i][j] = 0.0f;
    }

    const int vk = tid >> 4;               // 0..15, V loader row base
    const int vc = (tid & 15) * 4;         // V loader col

    for (int kt = 0; kt < 32; ++kt) {
        __syncthreads();                               // (A) buf reusable
        // ---- load K tile transposed + swizzled into buf ----
        {
            const int r0 = tid >> 5;
            const int c  = tid & 31;
            const int s  = 4 * (c & 15);
            #pragma unroll
            for (int p = 0; p < 8; ++p) {
                int rr = r0 + 8 * p;
                float4 kv4 = *(const float4*)(kg + (size_t)(kt * 64 + rr) * HID + 4 * c);
                buf[(4 * c + 0) * 64 + (rr ^ s)] = kv4.x;
                buf[(4 * c + 1) * 64 + (rr ^ s)] = kv4.y;
                buf[(4 * c + 2) * 64 + (rr ^ s)] = kv4.z;
                buf[(4 * c + 3) * 64 + (rr ^ s)] = kv4.w;
            }
        }
        __syncthreads();                               // (B) Kt visible

        // ---- S = Q @ K^T (64x64), register tile 4x4 ----
        float acc[4][4] = {};
        for (int d0 = 0; d0 < 128; d0 += 4) {
            const int s = 4 * ((d0 >> 2) & 15);
            #pragma unroll
            for (int dd = 0; dd < 4; ++dd) {
                const int d = d0 + dd;
                float4 a4 = *(const float4*)&Qt[d * 64 + ((4 * ty) ^ s)];
                float4 b4 = *(const float4*)&buf[d * 64 + ((4 * tx) ^ s)];
                float aa[4] = {a4.x, a4.y, a4.z, a4.w};
                float bb[4] = {b4.x, b4.y, b4.z, b4.w};
                #pragma unroll
                for (int i = 0; i < 4; ++i)
                    #pragma unroll
                    for (int j = 0; j < 4; ++j)
                        acc[i][j] = fmaf(aa[i], bb[j], acc[i][j]);
            }
        }

        // ---- prefetch V half 0 (overlaps softmax) ----
        float4 vpre0[4];
        #pragma unroll
        for (int p = 0; p < 4; ++p)
            vpre0[p] = *(const float4*)(vg + (size_t)(kt * 64 + vk + 16 * p) * HID + vc);

        // ---- online softmax on acc ----
        const float scale = 0.08838834764831843f;      // 1/sqrt(128)
        float rmax[4], rsum[4], alpha[4];
        #pragma unroll
        for (int i = 0; i < 4; ++i) {
            #pragma unroll
            for (int j = 0; j < 4; ++j) acc[i][j] *= scale;
            rmax[i] = fmaxf(fmaxf(acc[i][0], acc[i][1]), fmaxf(acc[i][2], acc[i][3]));
        }
        #pragma unroll
        for (int off = 1; off < 16; off <<= 1)
            #pragma unroll
            for (int i = 0; i < 4; ++i)
                rmax[i] = fmaxf(rmax[i], __shfl_xor(rmax[i], off));
        #pragma unroll
        for (int i = 0; i < 4; ++i) {
            float mn = fmaxf(m_i[i], rmax[i]);
            alpha[i] = __expf(m_i[i] - mn);
            m_i[i] = mn;
            rsum[i] = 0.0f;
            #pragma unroll
            for (int j = 0; j < 4; ++j) {
                acc[i][j] = __expf(acc[i][j] - mn);
                rsum[i] += acc[i][j];
            }
        }
        #pragma unroll
        for (int off = 1; off < 16; off <<= 1)
            #pragma unroll
            for (int i = 0; i < 4; ++i)
                rsum[i] += __shfl_xor(rsum[i], off);
        #pragma unroll
        for (int i = 0; i < 4; ++i) {
            l_i[i] = l_i[i] * alpha[i] + rsum[i];
            #pragma unroll
            for (int j = 0; j < 8; ++j) o[i][j] *= alpha[i];
        }

        __syncthreads();                               // (C) Kt reads done
        // ---- write P (swizzled) + V half 0 into buf ----
        #pragma unroll
        for (int i = 0; i < 4; ++i) {
            float4 pv = make_float4(acc[i][0], acc[i][1], acc[i][2], acc[i][3]);
            *(float4*)&Pb[(4 * ty + i) * 64 + ((4 * tx) ^ (4 * ty))] = pv;
        }
        #pragma unroll
        for (int p = 0; p < 4; ++p)
            *(float4*)&Vb[(vk + 16 * p) * 64 + vc] = vpre0[p];
        __syncthreads();                               // (D) P, Vh0 visible

        // ---- prefetch V half 1 (overlaps PV half 0) ----
        float4 vpre1[4];
        #pragma unroll
        for (int p = 0; p < 4; ++p)
            vpre1[p] = *(const float4*)(vg + (size_t)(kt * 64 + vk + 16 * p) * HID + 64 + vc);

        // ---- PV half 0 ----
        #pragma unroll 4
        for (int k0 = 0; k0 < 64; k0 += 4) {
            float a4[4][4];
            #pragma unroll
            for (int i = 0; i < 4; ++i) {
                float4 t = *(const float4*)&Pb[(4 * ty + i) * 64 + (k0 ^ (4 * ty))];
                a4[i][0] = t.x; a4[i][1] = t.y; a4[i][2] = t.z; a4[i][3] = t.w;
            }
            #pragma unroll
            for (int kk = 0; kk < 4; ++kk) {
                float4 b4 = *(const float4*)&Vb[(k0 + kk) * 64 + 4 * tx];
                #pragma unroll
                for (int i = 0; i < 4; ++i) {
                    o[i][0] = fmaf(a4[i][kk], b4.x, o[i][0]);
                    o[i][1] = fmaf(a4[i][kk], b4.y, o[i][1]);
                    o[i][2] = fmaf(a4[i][kk], b4.z, o[i][2]);
                    o[i][3] = fmaf(a4[i][kk], b4.w, o[i][3]);
                }
            }
        }
        __syncthreads();                               // (E) Vh0 reads done
        #pragma unroll
        for (int p = 0; p < 4; ++p)
            *(float4*)&Vb[(vk + 16 * p) * 64 + vc] = vpre1[p];
        __syncthreads();                               // (F) Vh1 visible

        // ---- PV half 1 ----
        #pragma unroll 4
        for (int k0 = 0; k0 < 64; k0 += 4) {
            float a4[4][4];
            #pragma unroll
            for (int i = 0; i < 4; ++i) {
                float4 t = *(const float4*)&Pb[(4 * ty + i) * 64 + (k0 ^ (4 * ty))];
                a4[i][0] = t.x; a4[i][1] = t.y; a4[i][2] = t.z; a4[i][3] = t.w;
            }
            #pragma unroll
            for (int kk = 0; kk < 4; ++kk) {
                float4 b4 = *(const float4*)&Vb[(k0 + kk) * 64 + 4 * tx];
                #pragma unroll
                for (int i = 0; i < 4; ++i) {
                    o[i][4] = fmaf(a4[i][kk], b4.x, o[i][4]);
                    o[i][5] = fmaf(a4[i][kk], b4.y, o[i][5]);
                    o[i][6] = fmaf(a4[i][kk], b4.z, o[i][6]);
                    o[i][7] = fmaf(a4[i][kk], b4.w, o[i][7]);
                }
            }
        }
    }

    // ---- epilogue: O /= l, store in-place over q ----
    #pragma unroll
    for (int i = 0; i < 4; ++i) {
        float inv = 1.0f / l_i[i];
        float* orow = qg + (size_t)(4 * ty + i) * HID;
        float4 o0 = make_float4(o[i][0] * inv, o[i][1] * inv, o[i][2] * inv, o[i][3] * inv);
        float4 o1 = make_float4(o[i][4] * inv, o[i][5] * inv, o[i][6] * inv, o[i][7] * inv);
        *(float4*)(orow + 4 * tx)      = o0;
        *(float4*)(orow + 64 + 4 * tx) = o1;
    }
}

extern "C" void kernel_launch(void* const* d_in, const int* in_sizes, int n_in,
                              void* d_out, int out_size, void* d_ws, size_t ws_size,
                              hipStream_t stream)
{
    const float* x     = (const float*)d_in[0];
    const float* slow  = (const float*)d_in[1];
    const float* Wq_in = (const float*)d_in[3];
    const float* bq_in = (const float*)d_in[4];
    const float* Wm    = (const float*)d_in[5];
    const float* bm    = (const float*)d_in[6];
    const float* Wq    = (const float*)d_in[7];
    const float* bq    = (const float*)d_in[8];
    const float* Wk    = (const float*)d_in[9];
    const float* bk    = (const float*)d_in[10];
    const float* Wv    = (const float*)d_in[11];
    const float* bv    = (const float*)d_in[12];
    const float* Wo    = (const float*)d_in[13];
    const float* bo    = (const float*)d_in[14];
    const float* g1    = (const float*)d_in[15];
    const float* be1   = (const float*)d_in[16];
    const float* W1    = (const float*)d_in[17];
    const float* b1    = (const float*)d_in[18];
    const float* W2    = (const float*)d_in[19];
    const float* b2    = (const float*)d_in[20];
    const float* g2    = (const float*)d_in[21];
    const float* be2   = (const float*)d_in[22];
    const float* M1    = (const float*)d_in[23];
    const float* bm1   = (const float*)d_in[24];
    const float* M2    = (const float*)d_in[25];
    const float* bm2   = (const float*)d_in[26];
    float* out = (float*)d_out;

    float* ws   = (float*)d_ws;
    float* q_in = ws;
    float* kv   = q_in + (size_t)MQ * HID;
    float* qb   = kv   + (size_t)MK * EMB;
    float* kb   = qb   + (size_t)MQ * HID;
    float* vb   = kb   + (size_t)MK * HID;
    float* ob   = vb   + (size_t)MK * HID;
    float* ffb  = ob   + (size_t)MQ * HID;

    dim3 blk(256);

    gemm_kernel<OP_BIAS><<<dim3(HID / BN, MQ / BM), blk, 0, stream>>>(
        slow, Wq_in, bq_in, nullptr, q_in, MQ, HID, DQ);
    gemm_kernel<OP_BIAS><<<dim3(EMB / BN, MK / BM), blk, 0, stream>>>(
        x, Wm, bm, nullptr, kv, MK, EMB, 4);
    gemm_kernel<OP_BIAS><<<dim3(HID / BN, MQ / BM), blk, 0, stream>>>(
        q_in, Wq, bq, nullptr, qb, MQ, HID, HID);
    gemm_kernel<OP_BIAS><<<dim3(HID / BN, MK / BM), blk, 0, stream>>>(
        kv, Wk, bk, nullptr, kb, MK, HID, EMB);
    gemm_kernel<OP_BIAS><<<dim3(HID / BN, MK / BM), blk, 0, stream>>>(
        kv, Wv, bv, nullptr, vb, MK, HID, EMB);
    rope_kernel<<<MQ, blk, 0, stream>>>(qb, ROWS_Q, 196, 14, MQ * 256);
    rope_kernel<<<MK, blk, 0, stream>>>(kb, ROWS_K, 64, 8, MK * 256);
    // flash attention (in-place into qb): 2 * 4 * 98 = 784 blocks
    fattn_kernel<<<dim3(BATCH * NH * 98), blk, 0, stream>>>(qb, kb, vb);
    gemm_kernel<OP_RES><<<dim3(HID / BN, MQ / BM), blk, 0, stream>>>(
        qb, Wo, bo, q_in, ob, MQ, HID, HID);
    ln_kernel<<<MQ / 4, blk, 0, stream>>>(ob, g1, be1);
    gemm_kernel<OP_GELU><<<dim3(FF / BN, MQ / BM), blk, 0, stream>>>(
        ob, W1, b1, nullptr, ffb, MQ, FF, HID);
    gemm_kernel<OP_RES><<<dim3(HID / BN, MQ / BM), blk, 0, stream>>>(
        ffb, W2, b2, ob, q_in, MQ, HID, FF);
    ln_kernel<<<MQ / 4, blk, 0, stream>>>(q_in, g2, be2);
    gemm_kernel<OP_GELU><<<dim3((2 * HID) / BN, MQ / BM), blk, 0, stream>>>(
        q_in, M1, bm1, nullptr, ffb, MQ, 2 * HID, HID);
    gemm_kernel<OP_BIAS><<<dim3(OUTD / BN, MQ / BM), blk, 0, stream>>>(
        ffb, M2, bm2, nullptr, out, MQ, OUTD, 2 * HID);
}

// Round 3
// 1519.947 us; speedup vs baseline: 7.1469x; 2.4180x over previous
//
#include <hip/hip_runtime.h>
#include <cstdint>
#include <cstddef>

// ---------------- dims ----------------
#define BATCH 2
#define MQ 12544          // B * TQ * NQ
#define ROWS_Q 6272
#define MK 4096           // B * T*H*W
#define ROWS_K 2048
#define HID 512
#define NH 4
#define HD 128
#define EMB 1024
#define DQ 896
#define FF 1024
#define OUTD 896

typedef __bf16 bf16;
typedef bf16 bf16x8 __attribute__((ext_vector_type(8)));
typedef float f32x4 __attribute__((ext_vector_type(4)));

enum { OP_BIAS = 0, OP_GELU = 1, OP_RES = 2 };

__device__ __forceinline__ float gelu_tanh(float x) {
    float x3 = x * x * x;
    return 0.5f * x * (1.0f + tanhf(0.7978845608028654f * (x + 0.044715f * x3)));
}

__device__ __forceinline__ void gld16(const bf16* g, bf16* l) {
    __builtin_amdgcn_global_load_lds(
        (const __attribute__((address_space(1))) unsigned int*)g,
        (__attribute__((address_space(3))) unsigned int*)l, 16, 0, 0);
}

// ---------------------------------------------------------------------------
// bf16 MFMA GEMM (m97 structure): C = A(MxK) @ Bt(NxK)^T + bias, epilogue OP.
// 128x128 tile, BK=32, 4 waves (2x2), each wave 4x4 grid of 16x16x32 MFMAs.
// M, N multiples of 128; K multiple of 32.
// ---------------------------------------------------------------------------
template <int OP, bool WF32, bool WB16>
__global__ __launch_bounds__(256) void mgemm(
    const bf16* __restrict__ A, const bf16* __restrict__ Bt,
    const float* __restrict__ bias, const float* __restrict__ res,
    float* __restrict__ Cf, bf16* __restrict__ Cb, int M, int N, int K)
{
    __shared__ __align__(16) bf16 As[128 * 32];
    __shared__ __align__(16) bf16 Bs[128 * 32];
    const int tid  = threadIdx.x;
    const int m0   = blockIdx.y * 128;
    const int n0   = blockIdx.x * 128;
    const int wave = tid >> 6, lane = tid & 63;
    const int wm = (wave >> 1) * 64, wn = (wave & 1) * 64;

    f32x4 acc[4][4] = {};

    // staging: thread tid covers LDS bytes [16*tid, 16*tid+16) of each half-tile
    const int srow = tid >> 2;              // 0..63
    const int scol = (tid & 3) * 8;
    const bf16* Ag = A  + (size_t)(m0 + srow) * K + scol;
    const bf16* Bg = Bt + (size_t)(n0 + srow) * K + scol;
    bf16* Al = &As[tid * 8];
    bf16* Bl = &Bs[tid * 8];
    const size_t half = (size_t)64 * K;

    const int fr = lane & 15;
    const int kq = (lane >> 4) * 8;
    const bf16* pa = &As[(wm + fr) * 32 + kq];
    const bf16* pb = &Bs[(wn + fr) * 32 + kq];

    for (int k0 = 0; k0 < K; k0 += 32) {
        gld16(Ag + k0,        Al);
        gld16(Ag + k0 + half, Al + 64 * 32);
        gld16(Bg + k0,        Bl);
        gld16(Bg + k0 + half, Bl + 64 * 32);
        __syncthreads();                 // drains vmcnt -> tiles visible

        bf16x8 af[4], bfr[4];
        #pragma unroll
        for (int i = 0; i < 4; ++i) af[i]  = *(const bf16x8*)(pa + i * 16 * 32);
        #pragma unroll
        for (int j = 0; j < 4; ++j) bfr[j] = *(const bf16x8*)(pb + j * 16 * 32);
        #pragma unroll
        for (int i = 0; i < 4; ++i)
            #pragma unroll
            for (int j = 0; j < 4; ++j)
                acc[i][j] = __builtin_amdgcn_mfma_f32_16x16x32_bf16(
                    af[i], bfr[j], acc[i][j], 0, 0, 0);
        __syncthreads();                 // reads done before next staging
    }

    // epilogue: C/D layout col=lane&15, row=(lane>>4)*4+r  [m89/m91 verified]
    const int colb = n0 + wn + (lane & 15);
    const int rowb = m0 + wm + (lane >> 4) * 4;
    #pragma unroll
    for (int i = 0; i < 4; ++i) {
        #pragma unroll
        for (int j = 0; j < 4; ++j) {
            const int c = colb + j * 16;
            const float bj = bias[c];
            #pragma unroll
            for (int r = 0; r < 4; ++r) {
                const int m = rowb + i * 16 + r;
                float v = acc[i][j][r] + bj;
                if (OP == OP_GELU) v = gelu_tanh(v);
                if (OP == OP_RES)  v += res[(size_t)m * N + c];
                if (WF32) Cf[(size_t)m * N + c] = v;
                if (WB16) Cb[(size_t)m * N + c] = (bf16)v;
            }
        }
    }
}

// W (KxN fp32) -> Wt (NxK bf16), 32x32 tiles. K,N multiples of 32.
__global__ __launch_bounds__(256) void transpose_kernel(
    const float* __restrict__ W, bf16* __restrict__ Wt, int K, int N)
{
    __shared__ float t[32][33];
    const int bx = blockIdx.x;   // n-tile
    const int by = blockIdx.y;   // k-tile
    const int x = threadIdx.x & 31, y = threadIdx.x >> 5;  // 32 x 8
    #pragma unroll
    for (int i = 0; i < 32; i += 8)
        t[y + i][x] = W[(size_t)(by * 32 + y + i) * N + bx * 32 + x];
    __syncthreads();
    #pragma unroll
    for (int i = 0; i < 32; i += 8)
        Wt[(size_t)(bx * 32 + y + i) * K + by * 32 + x] = (bf16)t[x][y + i];
}

// fp32 -> bf16 elementwise (n divisible by 4)
__global__ __launch_bounds__(256) void cvt_kernel(
    const float* __restrict__ in, bf16* __restrict__ out, int n4)
{
    int i = blockIdx.x * 256 + threadIdx.x;
    if (i >= n4) return;
    float4 v = ((const float4*)in)[i];
    out[4 * i + 0] = (bf16)v.x;
    out[4 * i + 1] = (bf16)v.y;
    out[4 * i + 2] = (bf16)v.z;
    out[4 * i + 3] = (bf16)v.w;
}

// kv = x @ Wm + bm  (K=4), bf16 out. One thread per output.
__global__ __launch_bounds__(256) void kv_kernel(
    const float* __restrict__ x, const float* __restrict__ Wm,
    const float* __restrict__ bm, bf16* __restrict__ kv)
{
    int idx = blockIdx.x * 256 + threadIdx.x;   // MK*EMB
    int r = idx >> 10, n = idx & 1023;
    float4 xv = *(const float4*)(x + (size_t)r * 4);
    float v = bm[n] + xv.x * Wm[n] + xv.y * Wm[1024 + n]
                    + xv.z * Wm[2048 + n] + xv.w * Wm[3072 + n];
    kv[idx] = (bf16)v;
}

// 3D RoPE in-place on (rows x 512) viewed as (rows, 4 heads, 128).
__global__ __launch_bounds__(256) void rope_kernel(
    float* __restrict__ buf, int tok, int gdiv, int wdiv, int total)
{
    int idx = blockIdx.x * 256 + threadIdx.x;
    if (idx >= total) return;
    int row = idx >> 8;
    int r2 = idx & 255;
    int h = r2 >> 6;
    int j = r2 & 63;
    int n = row % tok;
    int t = n / gdiv;
    int g = n % gdiv;
    int gh = g / wdiv;
    int gw = g % wdiv;
    float p = (j < 22) ? (float)t : (j < 43) ? (float)gh : (float)gw;
    float inv_freq = exp2f(-(float)j * 0.20762050593045954f);
    float fr = p * inv_freq;
    float c = cosf(fr), s = sinf(fr);
    size_t base = (size_t)row * 512 + (size_t)h * 128 + j;
    float x1 = buf[base], x2 = buf[base + 64];
    buf[base]      = x1 * c - x2 * s;
    buf[base + 64] = x2 * c + x1 * s;
}

// LayerNorm in-place on (rows x 512) + bf16 copy. One wave per row.
__global__ __launch_bounds__(256) void ln_kernel(
    float* __restrict__ xb, const float* __restrict__ g,
    const float* __restrict__ be, bf16* __restrict__ out16)
{
    int wave = threadIdx.x >> 6, lane = threadIdx.x & 63;
    size_t row = (size_t)blockIdx.x * 4 + wave;
    float* xp = xb + row * 512;
    float4 a = ((const float4*)xp)[lane];
    float4 b = ((const float4*)xp)[lane + 64];
    float s  = a.x + a.y + a.z + a.w + b.x + b.y + b.z + b.w;
    float sq = a.x*a.x + a.y*a.y + a.z*a.z + a.w*a.w
             + b.x*b.x + b.y*b.y + b.z*b.z + b.w*b.w;
    #pragma unroll
    for (int off = 32; off; off >>= 1) {
        s  += __shfl_xor(s, off);
        sq += __shfl_xor(sq, off);
    }
    float mean = s * (1.0f / 512.0f);
    float var  = sq * (1.0f / 512.0f) - mean * mean;
    float rstd = rsqrtf(var + 1e-5f);
    float4 gv1 = ((const float4*)g)[lane],  gv2 = ((const float4*)g)[lane + 64];
    float4 bv1 = ((const float4*)be)[lane], bv2 = ((const float4*)be)[lane + 64];
    a.x = (a.x - mean) * rstd * gv1.x + bv1.x;
    a.y = (a.y - mean) * rstd * gv1.y + bv1.y;
    a.z = (a.z - mean) * rstd * gv1.z + bv1.z;
    a.w = (a.w - mean) * rstd * gv1.w + bv1.w;
    b.x = (b.x - mean) * rstd * gv2.x + bv2.x;
    b.y = (b.y - mean) * rstd * gv2.y + bv2.y;
    b.z = (b.z - mean) * rstd * gv2.z + bv2.z;
    b.w = (b.w - mean) * rstd * gv2.w + bv2.w;
    ((float4*)xp)[lane]      = a;
    ((float4*)xp)[lane + 64] = b;
    bf16* op = out16 + row * 512;
    op[lane * 4 + 0] = (bf16)a.x;
    op[lane * 4 + 1] = (bf16)a.y;
    op[lane * 4 + 2] = (bf16)a.z;
    op[lane * 4 + 3] = (bf16)a.w;
    op[256 + lane * 4 + 0] = (bf16)b.x;
    op[256 + lane * 4 + 1] = (bf16)b.y;
    op[256 + lane * 4 + 2] = (bf16)b.z;
    op[256 + lane * 4 + 3] = (bf16)b.w;
}

// ---------------------------------------------------------------------------
// Flash attention (fp32), unchanged from round 2 (known correct).
// ---------------------------------------------------------------------------
__global__ __launch_bounds__(256, 2) void fattn_kernel(
    float* __restrict__ q, const float* __restrict__ k, const float* __restrict__ v)
{
    __shared__ float Qt[128 * 64];
    __shared__ float buf[8192];
    float* Pb = buf;
    float* Vb = buf + 4096;

    const int tid = threadIdx.x;
    const int tx = tid & 15, ty = tid >> 4;
    const int bid = blockIdx.x;
    const int qt = bid % 98;
    const int h  = (bid / 98) & 3;
    const int b  = bid / 392;

    float* qg       = q + ((size_t)(b * ROWS_Q + qt * 64)) * HID + h * HD;
    const float* kg = k + ((size_t)(b * ROWS_K)) * HID + h * HD;
    const float* vg = v + ((size_t)(b * ROWS_K)) * HID + h * HD;

    {
        const int r0 = tid >> 5;
        const int c  = tid & 31;
        const int s  = 4 * (c & 15);
        #pragma unroll
        for (int p = 0; p < 8; ++p) {
            int rr = r0 + 8 * p;
            float4 qv = *(const float4*)(qg + (size_t)rr * HID + 4 * c);
            Qt[(4 * c + 0) * 64 + (rr ^ s)] = qv.x;
            Qt[(4 * c + 1) * 64 + (rr ^ s)] = qv.y;
            Qt[(4 * c + 2) * 64 + (rr ^ s)] = qv.z;
            Qt[(4 * c + 3) * 64 + (rr ^ s)] = qv.w;
        }
    }

    float m_i[4], l_i[4], o[4][8];
    #pragma unroll
    for (int i = 0; i < 4; ++i) {
        m_i[i] = -1e30f; l_i[i] = 0.0f;
        #pragma unroll
        for (int j = 0; j < 8; ++j) o[i][j] = 0.0f;
    }

    const int vk = tid >> 4;
    const int vc = (tid & 15) * 4;

    for (int kt = 0; kt < 32; ++kt) {
        __syncthreads();
        {
            const int r0 = tid >> 5;
            const int c  = tid & 31;
            const int s  = 4 * (c & 15);
            #pragma unroll
            for (int p = 0; p < 8; ++p) {
                int rr = r0 + 8 * p;
                float4 kv4 = *(const float4*)(kg + (size_t)(kt * 64 + rr) * HID + 4 * c);
                buf[(4 * c + 0) * 64 + (rr ^ s)] = kv4.x;
                buf[(4 * c + 1) * 64 + (rr ^ s)] = kv4.y;
                buf[(4 * c + 2) * 64 + (rr ^ s)] = kv4.z;
                buf[(4 * c + 3) * 64 + (rr ^ s)] = kv4.w;
            }
        }
        __syncthreads();

        float acc[4][4] = {};
        for (int d0 = 0; d0 < 128; d0 += 4) {
            const int s = 4 * ((d0 >> 2) & 15);
            #pragma unroll
            for (int dd = 0; dd < 4; ++dd) {
                const int d = d0 + dd;
                float4 a4 = *(const float4*)&Qt[d * 64 + ((4 * ty) ^ s)];
                float4 b4 = *(const float4*)&buf[d * 64 + ((4 * tx) ^ s)];
                float aa[4] = {a4.x, a4.y, a4.z, a4.w};
                float bb[4] = {b4.x, b4.y, b4.z, b4.w};
                #pragma unroll
                for (int i = 0; i < 4; ++i)
                    #pragma unroll
                    for (int j = 0; j < 4; ++j)
                        acc[i][j] = fmaf(aa[i], bb[j], acc[i][j]);
            }
        }

        float4 vpre0[4];
        #pragma unroll
        for (int p = 0; p < 4; ++p)
            vpre0[p] = *(const float4*)(vg + (size_t)(kt * 64 + vk + 16 * p) * HID + vc);

        const float scale = 0.08838834764831843f;
        float rmax[4], rsum[4], alpha[4];
        #pragma unroll
        for (int i = 0; i < 4; ++i) {
            #pragma unroll
            for (int j = 0; j < 4; ++j) acc[i][j] *= scale;
            rmax[i] = fmaxf(fmaxf(acc[i][0], acc[i][1]), fmaxf(acc[i][2], acc[i][3]));
        }
        #pragma unroll
        for (int off = 1; off < 16; off <<= 1)
            #pragma unroll
            for (int i = 0; i < 4; ++i)
                rmax[i] = fmaxf(rmax[i], __shfl_xor(rmax[i], off));
        #pragma unroll
        for (int i = 0; i < 4; ++i) {
            float mn = fmaxf(m_i[i], rmax[i]);
            alpha[i] = __expf(m_i[i] - mn);
            m_i[i] = mn;
            rsum[i] = 0.0f;
            #pragma unroll
            for (int j = 0; j < 4; ++j) {
                acc[i][j] = __expf(acc[i][j] - mn);
                rsum[i] += acc[i][j];
            }
        }
        #pragma unroll
        for (int off = 1; off < 16; off <<= 1)
            #pragma unroll
            for (int i = 0; i < 4; ++i)
                rsum[i] += __shfl_xor(rsum[i], off);
        #pragma unroll
        for (int i = 0; i < 4; ++i) {
            l_i[i] = l_i[i] * alpha[i] + rsum[i];
            #pragma unroll
            for (int j = 0; j < 8; ++j) o[i][j] *= alpha[i];
        }

        __syncthreads();
        #pragma unroll
        for (int i = 0; i < 4; ++i) {
            float4 pv = make_float4(acc[i][0], acc[i][1], acc[i][2], acc[i][3]);
            *(float4*)&Pb[(4 * ty + i) * 64 + ((4 * tx) ^ (4 * ty))] = pv;
        }
        #pragma unroll
        for (int p = 0; p < 4; ++p)
            *(float4*)&Vb[(vk + 16 * p) * 64 + vc] = vpre0[p];
        __syncthreads();

        float4 vpre1[4];
        #pragma unroll
        for (int p = 0; p < 4; ++p)
            vpre1[p] = *(const float4*)(vg + (size_t)(kt * 64 + vk + 16 * p) * HID + 64 + vc);

        #pragma unroll 4
        for (int k0 = 0; k0 < 64; k0 += 4) {
            float a4[4][4];
            #pragma unroll
            for (int i = 0; i < 4; ++i) {
                float4 t = *(const float4*)&Pb[(4 * ty + i) * 64 + (k0 ^ (4 * ty))];
                a4[i][0] = t.x; a4[i][1] = t.y; a4[i][2] = t.z; a4[i][3] = t.w;
            }
            #pragma unroll
            for (int kk = 0; kk < 4; ++kk) {
                float4 b4 = *(const float4*)&Vb[(k0 + kk) * 64 + 4 * tx];
                #pragma unroll
                for (int i = 0; i < 4; ++i) {
                    o[i][0] = fmaf(a4[i][kk], b4.x, o[i][0]);
                    o[i][1] = fmaf(a4[i][kk], b4.y, o[i][1]);
                    o[i][2] = fmaf(a4[i][kk], b4.z, o[i][2]);
                    o[i][3] = fmaf(a4[i][kk], b4.w, o[i][3]);
                }
            }
        }
        __syncthreads();
        #pragma unroll
        for (int p = 0; p < 4; ++p)
            *(float4*)&Vb[(vk + 16 * p) * 64 + vc] = vpre1[p];
        __syncthreads();

        #pragma unroll 4
        for (int k0 = 0; k0 < 64; k0 += 4) {
            float a4[4][4];
            #pragma unroll
            for (int i = 0; i < 4; ++i) {
                float4 t = *(const float4*)&Pb[(4 * ty + i) * 64 + (k0 ^ (4 * ty))];
                a4[i][0] = t.x; a4[i][1] = t.y; a4[i][2] = t.z; a4[i][3] = t.w;
            }
            #pragma unroll
            for (int kk = 0; kk < 4; ++kk) {
                float4 b4 = *(const float4*)&Vb[(k0 + kk) * 64 + 4 * tx];
                #pragma unroll
                for (int i = 0; i < 4; ++i) {
                    o[i][4] = fmaf(a4[i][kk], b4.x, o[i][4]);
                    o[i][5] = fmaf(a4[i][kk], b4.y, o[i][5]);
                    o[i][6] = fmaf(a4[i][kk], b4.z, o[i][6]);
                    o[i][7] = fmaf(a4[i][kk], b4.w, o[i][7]);
                }
            }
        }
    }

    #pragma unroll
    for (int i = 0; i < 4; ++i) {
        float inv = 1.0f / l_i[i];
        float* orow = qg + (size_t)(4 * ty + i) * HID;
        float4 o0 = make_float4(o[i][0] * inv, o[i][1] * inv, o[i][2] * inv, o[i][3] * inv);
        float4 o1 = make_float4(o[i][4] * inv, o[i][5] * inv, o[i][6] * inv, o[i][7] * inv);
        *(float4*)(orow + 4 * tx)      = o0;
        *(float4*)(orow + 64 + 4 * tx) = o1;
    }
}

extern "C" void kernel_launch(void* const* d_in, const int* in_sizes, int n_in,
                              void* d_out, int out_size, void* d_ws, size_t ws_size,
                              hipStream_t stream)
{
    const float* x     = (const float*)d_in[0];
    const float* slow  = (const float*)d_in[1];
    const float* Wq_in = (const float*)d_in[3];
    const float* bq_in = (const float*)d_in[4];
    const float* Wm    = (const float*)d_in[5];
    const float* bm    = (const float*)d_in[6];
    const float* Wq    = (const float*)d_in[7];
    const float* bq    = (const float*)d_in[8];
    const float* Wk    = (const float*)d_in[9];
    const float* bk    = (const float*)d_in[10];
    const float* Wv    = (const float*)d_in[11];
    const float* bv    = (const float*)d_in[12];
    const float* Wo    = (const float*)d_in[13];
    const float* bo    = (const float*)d_in[14];
    const float* g1    = (const float*)d_in[15];
    const float* be1   = (const float*)d_in[16];
    const float* W1    = (const float*)d_in[17];
    const float* b1    = (const float*)d_in[18];
    const float* W2    = (const float*)d_in[19];
    const float* b2    = (const float*)d_in[20];
    const float* g2    = (const float*)d_in[21];
    const float* be2   = (const float*)d_in[22];
    const float* M1    = (const float*)d_in[23];
    const float* bm1   = (const float*)d_in[24];
    const float* M2    = (const float*)d_in[25];
    const float* bm2   = (const float*)d_in[26];
    float* out = (float*)d_out;

    // ---- workspace layout ----
    float* q_in_f = (float*)d_ws;                       // 12544*512
    float* qb = q_in_f + (size_t)MQ * HID;              // 12544*512
    float* kb = qb + (size_t)MQ * HID;                  // 4096*512
    float* vb = kb + (size_t)MK * HID;                  // 4096*512
    float* ob = vb + (size_t)MK * HID;                  // 12544*512
    bf16* shared_b = (bf16*)(ob + (size_t)MQ * HID);    // 12544*1024 (slow_b/attn_b/ff1_b/m1_b)
    bf16* q_in_b = shared_b + (size_t)MQ * FF;
    bf16* kv_b   = q_in_b + (size_t)MQ * HID;           // 4096*1024
    bf16* h_b    = kv_b + (size_t)MK * EMB;             // 12544*512 (h / h2)
    bf16* Wq_in_t = h_b + (size_t)MQ * HID;             // 512*896
    bf16* Wq_t = Wq_in_t + 512 * 896;                   // 512*512
    bf16* Wk_t = Wq_t + 512 * 512;                      // 512*1024
    bf16* Wv_t = Wk_t + 512 * 1024;
    bf16* Wo_t = Wv_t + 512 * 1024;                     // 512*512
    bf16* W1_t = Wo_t + 512 * 512;                      // 1024*512
    bf16* W2_t = W1_t + 1024 * 512;                     // 512*1024
    bf16* M1_t = W2_t + 512 * 1024;                     // 1024*512
    bf16* M2_t = M1_t + 1024 * 512;                     // 896*1024
    bf16* slow_b = shared_b;
    bf16* attn_b = shared_b;
    bf16* ff1_b  = shared_b;
    bf16* m1_b   = shared_b;

    dim3 blk(256);

    // ---- weight transposes (fp32 KxN -> bf16 NxK) ----
    transpose_kernel<<<dim3(512 / 32, 896 / 32),  blk, 0, stream>>>(Wq_in, Wq_in_t, 896, 512);
    transpose_kernel<<<dim3(512 / 32, 512 / 32),  blk, 0, stream>>>(Wq, Wq_t, 512, 512);
    transpose_kernel<<<dim3(512 / 32, 1024 / 32), blk, 0, stream>>>(Wk, Wk_t, 1024, 512);
    transpose_kernel<<<dim3(512 / 32, 1024 / 32), blk, 0, stream>>>(Wv, Wv_t, 1024, 512);
    transpose_kernel<<<dim3(512 / 32, 512 / 32),  blk, 0, stream>>>(Wo, Wo_t, 512, 512);
    transpose_kernel<<<dim3(1024 / 32, 512 / 32), blk, 0, stream>>>(W1, W1_t, 512, 1024);
    transpose_kernel<<<dim3(512 / 32, 1024 / 32), blk, 0, stream>>>(W2, W2_t, 1024, 512);
    transpose_kernel<<<dim3(1024 / 32, 512 / 32), blk, 0, stream>>>(M1, M1_t, 512, 1024);
    transpose_kernel<<<dim3(896 / 32, 1024 / 32), blk, 0, stream>>>(M2, M2_t, 1024, 896);

    // ---- activations to bf16 ----
    cvt_kernel<<<(MQ * DQ / 4 + 255) / 256, blk, 0, stream>>>(slow, slow_b, MQ * DQ / 4);
    kv_kernel<<<(MK * EMB) / 256, blk, 0, stream>>>(x, Wm, bm, kv_b);

    // 1. q_in = slow @ Wq_in + bq_in  -> fp32 (residual) + bf16 (next GEMM)
    mgemm<OP_BIAS, true, true><<<dim3(4, 98), blk, 0, stream>>>(
        slow_b, Wq_in_t, bq_in, nullptr, q_in_f, q_in_b, MQ, HID, DQ);
    // 2. q = q_in @ Wq + bq -> fp32 qb
    mgemm<OP_BIAS, true, false><<<dim3(4, 98), blk, 0, stream>>>(
        q_in_b, Wq_t, bq, nullptr, qb, nullptr, MQ, HID, HID);
    // 3. k = kv @ Wk + bk -> fp32 kb
    mgemm<OP_BIAS, true, false><<<dim3(4, 32), blk, 0, stream>>>(
        kv_b, Wk_t, bk, nullptr, kb, nullptr, MK, HID, EMB);
    // 4. v = kv @ Wv + bv -> fp32 vb
    mgemm<OP_BIAS, true, false><<<dim3(4, 32), blk, 0, stream>>>(
        kv_b, Wv_t, bv, nullptr, vb, nullptr, MK, HID, EMB);
    // 5. RoPE
    rope_kernel<<<MQ, blk, 0, stream>>>(qb, ROWS_Q, 196, 14, MQ * 256);
    rope_kernel<<<MK, blk, 0, stream>>>(kb, ROWS_K, 64, 8, MK * 256);
    // 6. flash attention in-place into qb
    fattn_kernel<<<dim3(BATCH * NH * 98), blk, 0, stream>>>(qb, kb, vb);
    // 7. attn out -> bf16
    cvt_kernel<<<(MQ * HID / 4 + 255) / 256, blk, 0, stream>>>(qb, attn_b, MQ * HID / 4);
    // 8. pre_ln = attn @ Wo + bo + q_in -> ob
    mgemm<OP_RES, true, false><<<dim3(4, 98), blk, 0, stream>>>(
        attn_b, Wo_t, bo, q_in_f, ob, nullptr, MQ, HID, HID);
    // 9. h = LN(ob) in-place + h_b
    ln_kernel<<<MQ / 4, blk, 0, stream>>>(ob, g1, be1, h_b);
    // 10. ff1 = gelu(h @ W1 + b1) -> bf16 only
    mgemm<OP_GELU, false, true><<<dim3(8, 98), blk, 0, stream>>>(
        h_b, W1_t, b1, nullptr, nullptr, ff1_b, MQ, FF, HID);
    // 11. pre2 = ff1 @ W2 + b2 + h -> q_in_f (reuse)
    mgemm<OP_RES, true, false><<<dim3(4, 98), blk, 0, stream>>>(
        ff1_b, W2_t, b2, ob, q_in_f, nullptr, MQ, HID, FF);
    // 12. h2 = LN(pre2) + h_b (reuse)
    ln_kernel<<<MQ / 4, blk, 0, stream>>>(q_in_f, g2, be2, h_b);
    // 13. m1 = gelu(h2 @ M1 + bm1) -> bf16 (reuse ff1_b)
    mgemm<OP_GELU, false, true><<<dim3(8, 98), blk, 0, stream>>>(
        h_b, M1_t, bm1, nullptr, nullptr, m1_b, MQ, 2 * HID, HID);
    // 14. out = m1 @ M2 + bm2 -> d_out
    mgemm<OP_BIAS, true, false><<<dim3(7, 98), blk, 0, stream>>>(
        m1_b, M2_t, bm2, nullptr, out, nullptr, MQ, OUTD, 2 * HID);
}

// Round 5
// 617.007 us; speedup vs baseline: 17.6058x; 2.4634x over previous
//
#include <hip/hip_runtime.h>
#include <cstdint>
#include <cstddef>

// ---------------- dims ----------------
#define BATCH 2
#define MQ 12544          // B * TQ * NQ
#define ROWS_Q 6272
#define MK 4096           // B * T*H*W
#define ROWS_K 2048
#define HID 512
#define NH 4
#define HD 128
#define EMB 1024
#define DQ 896
#define FF 1024
#define OUTD 896

typedef __bf16 bf16;
typedef unsigned int u32;
typedef bf16 bf16x8 __attribute__((ext_vector_type(8)));
typedef float f32x4 __attribute__((ext_vector_type(4)));

enum { OP_BIAS = 0, OP_GELU = 1, OP_RES = 2 };

__device__ __forceinline__ float gelu_tanh(float x) {
    float x3 = x * x * x;
    return 0.5f * x * (1.0f + tanhf(0.7978845608028654f * (x + 0.044715f * x3)));
}

__device__ __forceinline__ void gld16(const bf16* g, bf16* l) {
    __builtin_amdgcn_global_load_lds(
        (const __attribute__((address_space(1))) unsigned int*)g,
        (__attribute__((address_space(3))) unsigned int*)l, 16, 0, 0);
}

__device__ __forceinline__ u32 pack_bf16(float a, float b) {
    union { bf16 h[2]; u32 w; } u;
    u.h[0] = (bf16)a; u.h[1] = (bf16)b;
    return u.w;
}

// ---------------------------------------------------------------------------
// bf16 MFMA GEMM (m97 structure): C = A(MxK) @ Bt(NxK)^T + bias, epilogue OP.
// ---------------------------------------------------------------------------
template <int OP, bool WF32, bool WB16>
__global__ __launch_bounds__(256) void mgemm(
    const bf16* __restrict__ A, const bf16* __restrict__ Bt,
    const float* __restrict__ bias, const float* __restrict__ res,
    float* __restrict__ Cf, bf16* __restrict__ Cb, int M, int N, int K)
{
    __shared__ __align__(16) bf16 As[128 * 32];
    __shared__ __align__(16) bf16 Bs[128 * 32];
    const int tid  = threadIdx.x;
    const int m0   = blockIdx.y * 128;
    const int n0   = blockIdx.x * 128;
    const int wave = tid >> 6, lane = tid & 63;
    const int wm = (wave >> 1) * 64, wn = (wave & 1) * 64;

    f32x4 acc[4][4] = {};

    const int srow = tid >> 2;
    const int scol = (tid & 3) * 8;
    const bf16* Ag = A  + (size_t)(m0 + srow) * K + scol;
    const bf16* Bg = Bt + (size_t)(n0 + srow) * K + scol;
    bf16* Al = &As[tid * 8];
    bf16* Bl = &Bs[tid * 8];
    const size_t half = (size_t)64 * K;

    const int fr = lane & 15;
    const int kq = (lane >> 4) * 8;
    const bf16* pa = &As[(wm + fr) * 32 + kq];
    const bf16* pb = &Bs[(wn + fr) * 32 + kq];

    for (int k0 = 0; k0 < K; k0 += 32) {
        gld16(Ag + k0,        Al);
        gld16(Ag + k0 + half, Al + 64 * 32);
        gld16(Bg + k0,        Bl);
        gld16(Bg + k0 + half, Bl + 64 * 32);
        __syncthreads();

        bf16x8 af[4], bfr[4];
        #pragma unroll
        for (int i = 0; i < 4; ++i) af[i]  = *(const bf16x8*)(pa + i * 16 * 32);
        #pragma unroll
        for (int j = 0; j < 4; ++j) bfr[j] = *(const bf16x8*)(pb + j * 16 * 32);
        #pragma unroll
        for (int i = 0; i < 4; ++i)
            #pragma unroll
            for (int j = 0; j < 4; ++j)
                acc[i][j] = __builtin_amdgcn_mfma_f32_16x16x32_bf16(
                    af[i], bfr[j], acc[i][j], 0, 0, 0);
        __syncthreads();
    }

    const int colb = n0 + wn + (lane & 15);
    const int rowb = m0 + wm + (lane >> 4) * 4;
    #pragma unroll
    for (int i = 0; i < 4; ++i) {
        #pragma unroll
        for (int j = 0; j < 4; ++j) {
            const int c = colb + j * 16;
            const float bj = bias[c];
            #pragma unroll
            for (int r = 0; r < 4; ++r) {
                const int m = rowb + i * 16 + r;
                float v = acc[i][j][r] + bj;
                if (OP == OP_GELU) v = gelu_tanh(v);
                if (OP == OP_RES)  v += res[(size_t)m * N + c];
                if (WF32) Cf[(size_t)m * N + c] = v;
                if (WB16) Cb[(size_t)m * N + c] = (bf16)v;
            }
        }
    }
}

// W (KxN fp32) -> Wt (NxK bf16), 32x32 tiles.
__global__ __launch_bounds__(256) void transpose_kernel(
    const float* __restrict__ W, bf16* __restrict__ Wt, int K, int N)
{
    __shared__ float t[32][33];
    const int bx = blockIdx.x;
    const int by = blockIdx.y;
    const int x = threadIdx.x & 31, y = threadIdx.x >> 5;
    #pragma unroll
    for (int i = 0; i < 32; i += 8)
        t[y + i][x] = W[(size_t)(by * 32 + y + i) * N + bx * 32 + x];
    __syncthreads();
    #pragma unroll
    for (int i = 0; i < 32; i += 8)
        Wt[(size_t)(bx * 32 + y + i) * K + by * 32 + x] = (bf16)t[x][y + i];
}

// fp32 -> bf16 elementwise
__global__ __launch_bounds__(256) void cvt_kernel(
    const float* __restrict__ in, bf16* __restrict__ out, int n4)
{
    int i = blockIdx.x * 256 + threadIdx.x;
    if (i >= n4) return;
    float4 v = ((const float4*)in)[i];
    out[4 * i + 0] = (bf16)v.x;
    out[4 * i + 1] = (bf16)v.y;
    out[4 * i + 2] = (bf16)v.z;
    out[4 * i + 3] = (bf16)v.w;
}

// kv = x @ Wm + bm  (K=4), bf16 out.
__global__ __launch_bounds__(256) void kv_kernel(
    const float* __restrict__ x, const float* __restrict__ Wm,
    const float* __restrict__ bm, bf16* __restrict__ kv)
{
    int idx = blockIdx.x * 256 + threadIdx.x;
    int r = idx >> 10, n = idx & 1023;
    float4 xv = *(const float4*)(x + (size_t)r * 4);
    float v = bm[n] + xv.x * Wm[n] + xv.y * Wm[1024 + n]
                    + xv.z * Wm[2048 + n] + xv.w * Wm[3072 + n];
    kv[idx] = (bf16)v;
}

// 3D RoPE: bf16 in -> bf16 out (out-of-place), optional scale folded in.
__global__ __launch_bounds__(256) void rope_b_kernel(
    const bf16* __restrict__ in, bf16* __restrict__ out,
    int tok, int gdiv, int wdiv, int total, float sc)
{
    int idx = blockIdx.x * 256 + threadIdx.x;
    if (idx >= total) return;
    int row = idx >> 7;
    int r2 = idx & 127;
    int h = r2 >> 5;
    int j2 = r2 & 31;
    int j = 2 * j2;
    int n = row % tok;
    int t = n / gdiv;
    int g = n % gdiv;
    int gh = g / wdiv;
    int gw = g % wdiv;
    float pa = (j < 22) ? (float)t : (j < 43) ? (float)gh : (float)gw;
    int j1 = j + 1;
    float pb = (j1 < 22) ? (float)t : (j1 < 43) ? (float)gh : (float)gw;
    float fra = pa * exp2f(-(float)j  * 0.20762050593045954f);
    float frb = pb * exp2f(-(float)j1 * 0.20762050593045954f);
    float ca = cosf(fra), sa = sinf(fra);
    float cb = cosf(frb), sb = sinf(frb);
    size_t base = (size_t)row * 512 + (size_t)h * 128 + j;
    union { u32 w; bf16 e[2]; } ua, ub;
    ua.w = *(const u32*)(in + base);
    ub.w = *(const u32*)(in + base + 64);
    float x1a = (float)ua.e[0], x1b = (float)ua.e[1];
    float x2a = (float)ub.e[0], x2b = (float)ub.e[1];
    *(u32*)(out + base)      = pack_bf16((x1a * ca - x2a * sa) * sc,
                                         (x1b * cb - x2b * sb) * sc);
    *(u32*)(out + base + 64) = pack_bf16((x2a * ca + x1a * sa) * sc,
                                         (x2b * cb + x1b * sb) * sc);
}

// v16 (MK x 512, head-interleaved) -> Vt[b][h][d][2048] bf16
__global__ __launch_bounds__(256) void vt_kernel(
    const bf16* __restrict__ v16, bf16* __restrict__ vt)
{
    int idx = blockIdx.x * 256 + threadIdx.x;   // 8*128*2048 = 2M
    int t = idx & 2047;
    int d = (idx >> 11) & 127;
    int bh = idx >> 18;
    int b = bh >> 2, h = bh & 3;
    vt[idx] = v16[(size_t)(b * ROWS_K + t) * HID + h * HD + d];
}

// LayerNorm in-place on (rows x 512) + bf16 copy.
__global__ __launch_bounds__(256) void ln_kernel(
    float* __restrict__ xb, const float* __restrict__ g,
    const float* __restrict__ be, bf16* __restrict__ out16)
{
    int wave = threadIdx.x >> 6, lane = threadIdx.x & 63;
    size_t row = (size_t)blockIdx.x * 4 + wave;
    float* xp = xb + row * 512;
    float4 a = ((const float4*)xp)[lane];
    float4 b = ((const float4*)xp)[lane + 64];
    float s  = a.x + a.y + a.z + a.w + b.x + b.y + b.z + b.w;
    float sq = a.x*a.x + a.y*a.y + a.z*a.z + a.w*a.w
             + b.x*b.x + b.y*b.y + b.z*b.z + b.w*b.w;
    #pragma unroll
    for (int off = 32; off; off >>= 1) {
        s  += __shfl_xor(s, off);
        sq += __shfl_xor(sq, off);
    }
    float mean = s * (1.0f / 512.0f);
    float var  = sq * (1.0f / 512.0f) - mean * mean;
    float rstd = rsqrtf(var + 1e-5f);
    float4 gv1 = ((const float4*)g)[lane],  gv2 = ((const float4*)g)[lane + 64];
    float4 bv1 = ((const float4*)be)[lane], bv2 = ((const float4*)be)[lane + 64];
    a.x = (a.x - mean) * rstd * gv1.x + bv1.x;
    a.y = (a.y - mean) * rstd * gv1.y + bv1.y;
    a.z = (a.z - mean) * rstd * gv1.z + bv1.z;
    a.w = (a.w - mean) * rstd * gv1.w + bv1.w;
    b.x = (b.x - mean) * rstd * gv2.x + bv2.x;
    b.y = (b.y - mean) * rstd * gv2.y + bv2.y;
    b.z = (b.z - mean) * rstd * gv2.z + bv2.z;
    b.w = (b.w - mean) * rstd * gv2.w + bv2.w;
    ((float4*)xp)[lane]      = a;
    ((float4*)xp)[lane + 64] = b;
    bf16* op = out16 + row * 512;
    *(u32*)(op + lane * 4)       = pack_bf16(a.x, a.y);
    *(u32*)(op + lane * 4 + 2)   = pack_bf16(a.z, a.w);
    *(u32*)(op + 256 + lane * 4)     = pack_bf16(b.x, b.y);
    *(u32*)(op + 256 + lane * 4 + 2) = pack_bf16(b.z, b.w);
}

// ---------------------------------------------------------------------------
// MFMA flash attention (bf16 inputs, fp32 accum).
// Computes S^T = K.Q^T so softmax stats live on the lane-col (q) axis and
// P^T B-frags are built with cross-lane shuffles (no LDS round-trip).
// Then O^T = V^T.P^T. Block = 4 waves x 32 q = 128 q rows; 49 blocks/(b,h).
// qs: RoPE'd, PRE-SCALED by 1/sqrt(128). vt: [b][h][d][2048].
// ---------------------------------------------------------------------------
__global__ __launch_bounds__(256, 2) void mattn_kernel(
    const bf16* __restrict__ qs, const bf16* __restrict__ ks,
    const bf16* __restrict__ vt, bf16* __restrict__ outb)
{
    __shared__ __align__(16) char smem[35840];
    bf16* Ksh = (bf16*)smem;            // [64][136]  (pad 8)
    bf16* Vsh = (bf16*)(smem + 17408);  // [128][72]  (pad 8)

    const int tid = threadIdx.x;
    const int wave = tid >> 6, lane = tid & 63;
    const int quad = lane >> 4, c = lane & 15;
    const int bid = blockIdx.x;
    const int qt = bid % 49;
    const int h  = (bid / 49) & 3;
    const int b  = bid / 196;

    const int q0 = qt * 128 + wave * 32;
    const bf16* qg = qs + (size_t)(b * ROWS_Q + q0) * HID + h * HD;
    const bf16* kg = ks + (size_t)(b * ROWS_K) * HID + h * HD;
    const bf16* vg = vt + (size_t)(b * NH + h) * HD * ROWS_K;

    // Q B-frags (reused across all K-tiles): qf[n][kstep]
    bf16x8 qf[2][4];
    #pragma unroll
    for (int n = 0; n < 2; ++n)
        #pragma unroll
        for (int s = 0; s < 4; ++s)
            qf[n][s] = *(const bf16x8*)(qg + (size_t)(n * 16 + c) * HID + s * 32 + quad * 8);

    f32x4 o[8][2] = {};                 // O^T acc: [d-tile][q-tile]
    float m_i[2] = {-1e30f, -1e30f}, l_i[2] = {0.0f, 0.0f};

    const int st_t = tid >> 2;          // K stage row
    const int st_d = (tid & 3) * 32;
    const int sv_d = tid >> 1;          // V stage row
    const int sv_t = (tid & 1) * 32;

    for (int kt = 0; kt < 32; ++kt) {
        __syncthreads();
        // stage K tile (64 x 128) row-major, stride 136
        {
            const bf16* src = kg + (size_t)(kt * 64 + st_t) * HID + st_d;
            bf16* dst = Ksh + st_t * 136 + st_d;
            #pragma unroll
            for (int i = 0; i < 4; ++i)
                *(bf16x8*)(dst + i * 8) = *(const bf16x8*)(src + i * 8);
        }
        // stage V^T tile (128 x 64) d-major, stride 72
        {
            const bf16* src = vg + (size_t)sv_d * ROWS_K + kt * 64 + sv_t;
            bf16* dst = Vsh + sv_d * 72 + sv_t;
            #pragma unroll
            for (int i = 0; i < 4; ++i)
                *(bf16x8*)(dst + i * 8) = *(const bf16x8*)(src + i * 8);
        }
        __syncthreads();

        // ---- S^T = K @ Q^T : s[token-tile][q-tile] ----
        f32x4 s[4][2] = {};
        #pragma unroll
        for (int ksi = 0; ksi < 4; ++ksi) {
            bf16x8 kf[4];
            #pragma unroll
            for (int mi = 0; mi < 4; ++mi)
                kf[mi] = *(const bf16x8*)(Ksh + (mi * 16 + c) * 136 + ksi * 32 + quad * 8);
            #pragma unroll
            for (int mi = 0; mi < 4; ++mi)
                #pragma unroll
                for (int n = 0; n < 2; ++n)
                    s[mi][n] = __builtin_amdgcn_mfma_f32_16x16x32_bf16(
                        kf[mi], qf[n][ksi], s[mi][n], 0, 0, 0);
        }

        // ---- online softmax per q (lane-col) ----
        float alpha[2];
        #pragma unroll
        for (int n = 0; n < 2; ++n) {
            float mx = -1e30f;
            #pragma unroll
            for (int mi = 0; mi < 4; ++mi)
                #pragma unroll
                for (int r = 0; r < 4; ++r) mx = fmaxf(mx, s[mi][n][r]);
            mx = fmaxf(mx, __shfl_xor(mx, 16));
            mx = fmaxf(mx, __shfl_xor(mx, 32));
            float mn = fmaxf(m_i[n], mx);
            alpha[n] = __expf(m_i[n] - mn);
            m_i[n] = mn;
            float sm = 0.0f;
            #pragma unroll
            for (int mi = 0; mi < 4; ++mi)
                #pragma unroll
                for (int r = 0; r < 4; ++r) {
                    float p = __expf(s[mi][n][r] - mn);
                    s[mi][n][r] = p;
                    sm += p;
                }
            sm += __shfl_xor(sm, 16);
            sm += __shfl_xor(sm, 32);
            l_i[n] = l_i[n] * alpha[n] + sm;
            #pragma unroll
            for (int md = 0; md < 8; ++md) {
                o[md][n][0] *= alpha[n]; o[md][n][1] *= alpha[n];
                o[md][n][2] *= alpha[n]; o[md][n][3] *= alpha[n];
            }
        }

        // ---- pack P and build P^T B-frags via cross-lane shuffles ----
        u32 pk[4][2][2];
        #pragma unroll
        for (int mi = 0; mi < 4; ++mi)
            #pragma unroll
            for (int n = 0; n < 2; ++n) {
                pk[mi][n][0] = pack_bf16(s[mi][n][0], s[mi][n][1]);
                pk[mi][n][1] = pack_bf16(s[mi][n][2], s[mi][n][3]);
            }
        bf16x8 pf[2][2];
        #pragma unroll
        for (int kst = 0; kst < 2; ++kst)
            #pragma unroll
            for (int n = 0; n < 2; ++n) {
                union { bf16x8 v8; u32 d[4]; } u;
                #pragma unroll
                for (int dw = 0; dw < 4; ++dw) {
                    int srcl = ((quad & 1) * 2 + (dw >> 1)) * 16 + c;
                    u32 lo = (u32)__shfl((int)pk[2 * kst][n][dw & 1], srcl);
                    u32 hi = (u32)__shfl((int)pk[2 * kst + 1][n][dw & 1], srcl);
                    u.d[dw] = (quad >= 2) ? hi : lo;
                }
                pf[kst][n] = u.v8;
            }

        // ---- O^T += V^T @ P^T ----
        #pragma unroll
        for (int kst = 0; kst < 2; ++kst)
            #pragma unroll
            for (int md = 0; md < 8; ++md) {
                bf16x8 vf = *(const bf16x8*)(Vsh + (md * 16 + c) * 72 + kst * 32 + quad * 8);
                #pragma unroll
                for (int n = 0; n < 2; ++n)
                    o[md][n] = __builtin_amdgcn_mfma_f32_16x16x32_bf16(
                        vf, pf[kst][n], o[md][n], 0, 0, 0);
            }
    }

    // ---- epilogue: divide by l, transpose via LDS, coalesced bf16 store ----
    __syncthreads();
    bf16* Osh = (bf16*)smem + wave * (32 * 136);   // [32 q][136 d-pad]
    float inv[2] = {1.0f / l_i[0], 1.0f / l_i[1]};
    #pragma unroll
    for (int md = 0; md < 8; ++md)
        #pragma unroll
        for (int n = 0; n < 2; ++n)
            #pragma unroll
            for (int hh = 0; hh < 2; ++hh) {
                u32 w = pack_bf16(o[md][n][2 * hh] * inv[n], o[md][n][2 * hh + 1] * inv[n]);
                int d = md * 16 + quad * 4 + 2 * hh;
                int qq = n * 16 + c;
                *(u32*)(Osh + qq * 136 + d) = w;
            }
    __syncthreads();
    bf16* og = outb + (size_t)(b * ROWS_Q + q0) * HID + h * HD;
    #pragma unroll
    for (int i = 0; i < 8; ++i) {
        int idx = i * 64 + lane;
        int qq = idx >> 4;
        int ch = idx & 15;
        bf16x8 vv = *(const bf16x8*)(Osh + qq * 136 + ch * 8);
        *(bf16x8*)(og + (size_t)qq * HID + ch * 8) = vv;
    }
}

extern "C" void kernel_launch(void* const* d_in, const int* in_sizes, int n_in,
                              void* d_out, int out_size, void* d_ws, size_t ws_size,
                              hipStream_t stream)
{
    const float* x     = (const float*)d_in[0];
    const float* slow  = (const float*)d_in[1];
    const float* Wq_in = (const float*)d_in[3];
    const float* bq_in = (const float*)d_in[4];
    const float* Wm    = (const float*)d_in[5];
    const float* bm    = (const float*)d_in[6];
    const float* Wq    = (const float*)d_in[7];
    const float* bq    = (const float*)d_in[8];
    const float* Wk    = (const float*)d_in[9];
    const float* bk    = (const float*)d_in[10];
    const float* Wv    = (const float*)d_in[11];
    const float* bv    = (const float*)d_in[12];
    const float* Wo    = (const float*)d_in[13];
    const float* bo    = (const float*)d_in[14];
    const float* g1    = (const float*)d_in[15];
    const float* be1   = (const float*)d_in[16];
    const float* W1    = (const float*)d_in[17];
    const float* b1    = (const float*)d_in[18];
    const float* W2    = (const float*)d_in[19];
    const float* b2    = (const float*)d_in[20];
    const float* g2    = (const float*)d_in[21];
    const float* be2   = (const float*)d_in[22];
    const float* M1    = (const float*)d_in[23];
    const float* bm1   = (const float*)d_in[24];
    const float* M2    = (const float*)d_in[25];
    const float* bm2   = (const float*)d_in[26];
    float* out = (float*)d_out;

    // ---- workspace layout ----
    float* q_in_f = (float*)d_ws;                         // MQ*512 f32
    float* ob     = q_in_f + (size_t)MQ * HID;            // MQ*512 f32
    bf16* shared_b = (bf16*)(ob + (size_t)MQ * HID);      // MQ*1024 (slow_b/attn_b/ff1_b/m1_b)
    bf16* q_in_b = shared_b + (size_t)MQ * FF;            // MQ*512
    bf16* kv_b   = q_in_b + (size_t)MQ * HID;             // MK*1024
    bf16* h_b    = kv_b + (size_t)MK * EMB;               // MQ*512
    bf16* q16    = h_b + (size_t)MQ * HID;                // MQ*512
    bf16* k16    = q16 + (size_t)MQ * HID;                // MK*512
    bf16* v16    = k16 + (size_t)MK * HID;                // MK*512
    bf16* qbt    = v16 + (size_t)MK * HID;                // MQ*512
    bf16* kbt    = qbt + (size_t)MQ * HID;                // MK*512
    bf16* Vt     = kbt + (size_t)MK * HID;                // 8*128*2048
    bf16* Wq_in_t = Vt + (size_t)8 * HD * ROWS_K;
    bf16* Wq_t = Wq_in_t + 512 * 896;
    bf16* Wk_t = Wq_t + 512 * 512;
    bf16* Wv_t = Wk_t + 512 * 1024;
    bf16* Wo_t = Wv_t + 512 * 1024;
    bf16* W1_t = Wo_t + 512 * 512;
    bf16* W2_t = W1_t + 1024 * 512;
    bf16* M1_t = W2_t + 512 * 1024;
    bf16* M2_t = M1_t + 1024 * 512;
    bf16* slow_b = shared_b;
    bf16* attn_b = shared_b;
    bf16* ff1_b  = shared_b;
    bf16* m1_b   = shared_b;

    dim3 blk(256);

    transpose_kernel<<<dim3(512 / 32, 896 / 32),  blk, 0, stream>>>(Wq_in, Wq_in_t, 896, 512);
    transpose_kernel<<<dim3(512 / 32, 512 / 32),  blk, 0, stream>>>(Wq, Wq_t, 512, 512);
    transpose_kernel<<<dim3(512 / 32, 1024 / 32), blk, 0, stream>>>(Wk, Wk_t, 1024, 512);
    transpose_kernel<<<dim3(512 / 32, 1024 / 32), blk, 0, stream>>>(Wv, Wv_t, 1024, 512);
    transpose_kernel<<<dim3(512 / 32, 512 / 32),  blk, 0, stream>>>(Wo, Wo_t, 512, 512);
    transpose_kernel<<<dim3(1024 / 32, 512 / 32), blk, 0, stream>>>(W1, W1_t, 512, 1024);
    transpose_kernel<<<dim3(512 / 32, 1024 / 32), blk, 0, stream>>>(W2, W2_t, 1024, 512);
    transpose_kernel<<<dim3(1024 / 32, 512 / 32), blk, 0, stream>>>(M1, M1_t, 512, 1024);
    transpose_kernel<<<dim3(896 / 32, 1024 / 32), blk, 0, stream>>>(M2, M2_t, 1024, 896);

    cvt_kernel<<<(MQ * DQ / 4 + 255) / 256, blk, 0, stream>>>(slow, slow_b, MQ * DQ / 4);
    kv_kernel<<<(MK * EMB) / 256, blk, 0, stream>>>(x, Wm, bm, kv_b);

    // q_in = slow @ Wq_in + bq_in -> fp32 (residual) + bf16
    mgemm<OP_BIAS, true, true><<<dim3(4, 98), blk, 0, stream>>>(
        slow_b, Wq_in_t, bq_in, nullptr, q_in_f, q_in_b, MQ, HID, DQ);
    // q/k/v projections -> bf16
    mgemm<OP_BIAS, false, true><<<dim3(4, 98), blk, 0, stream>>>(
        q_in_b, Wq_t, bq, nullptr, nullptr, q16, MQ, HID, HID);
    mgemm<OP_BIAS, false, true><<<dim3(4, 32), blk, 0, stream>>>(
        kv_b, Wk_t, bk, nullptr, nullptr, k16, MK, HID, EMB);
    mgemm<OP_BIAS, false, true><<<dim3(4, 32), blk, 0, stream>>>(
        kv_b, Wv_t, bv, nullptr, nullptr, v16, MK, HID, EMB);
    // RoPE (q pre-scaled by 1/sqrt(128)); V transpose
    rope_b_kernel<<<(MQ * 128 + 255) / 256, blk, 0, stream>>>(
        q16, qbt, ROWS_Q, 196, 14, MQ * 128, 0.08838834764831843f);
    rope_b_kernel<<<(MK * 128 + 255) / 256, blk, 0, stream>>>(
        k16, kbt, ROWS_K, 64, 8, MK * 128, 1.0f);
    vt_kernel<<<(8 * HD * ROWS_K) / 256, blk, 0, stream>>>(v16, Vt);
    // MFMA flash attention -> attn_b (bf16)
    mattn_kernel<<<dim3(392), blk, 0, stream>>>(qbt, kbt, Vt, attn_b);
    // pre_ln = attn @ Wo + bo + q_in
    mgemm<OP_RES, true, false><<<dim3(4, 98), blk, 0, stream>>>(
        attn_b, Wo_t, bo, q_in_f, ob, nullptr, MQ, HID, HID);
    ln_kernel<<<MQ / 4, blk, 0, stream>>>(ob, g1, be1, h_b);
    mgemm<OP_GELU, false, true><<<dim3(8, 98), blk, 0, stream>>>(
        h_b, W1_t, b1, nullptr, nullptr, ff1_b, MQ, FF, HID);
    mgemm<OP_RES, true, false><<<dim3(4, 98), blk, 0, stream>>>(
        ff1_b, W2_t, b2, ob, q_in_f, nullptr, MQ, HID, FF);
    ln_kernel<<<MQ / 4, blk, 0, stream>>>(q_in_f, g2, be2, h_b);
    mgemm<OP_GELU, false, true><<<dim3(8, 98), blk, 0, stream>>>(
        h_b, M1_t, bm1, nullptr, nullptr, m1_b, MQ, 2 * HID, HID);
    mgemm<OP_BIAS, true, false><<<dim3(7, 98), blk, 0, stream>>>(
        m1_b, M2_t, bm2, nullptr, out, nullptr, MQ, OUTD, 2 * HID);
}

// Round 6
// 579.949 us; speedup vs baseline: 18.7308x; 1.0639x over previous
//
#include <hip/hip_runtime.h>
#include <cstdint>
#include <cstddef>

// ---------------- dims ----------------
#define BATCH 2
#define MQ 12544          // B * TQ * NQ
#define ROWS_Q 6272
#define MK 4096           // B * T*H*W
#define ROWS_K 2048
#define HID 512
#define NH 4
#define HD 128
#define EMB 1024
#define DQ 896
#define FF 1024
#define OUTD 896

typedef __bf16 bf16;
typedef unsigned int u32;
typedef bf16 bf16x8 __attribute__((ext_vector_type(8)));
typedef bf16 bf16x4 __attribute__((ext_vector_type(4)));
typedef float f32x4 __attribute__((ext_vector_type(4)));

enum { OP_BIAS = 0, OP_GELU = 1, OP_RES = 2 };

__device__ __forceinline__ float gelu_tanh(float x) {
    float x3 = x * x * x;
    return 0.5f * x * (1.0f + tanhf(0.7978845608028654f * (x + 0.044715f * x3)));
}

__device__ __forceinline__ void gld16(const bf16* g, bf16* l) {
    __builtin_amdgcn_global_load_lds(
        (const __attribute__((address_space(1))) unsigned int*)g,
        (__attribute__((address_space(3))) unsigned int*)l, 16, 0, 0);
}

__device__ __forceinline__ u32 pack_bf16(float a, float b) {
    union { bf16 h[2]; u32 w; } u;
    u.h[0] = (bf16)a; u.h[1] = (bf16)b;
    return u.w;
}

// ---------------------------------------------------------------------------
// bf16 MFMA GEMM, 128x128 tile (m97 structure). For N>=1024-ish shapes.
// ---------------------------------------------------------------------------
template <int OP, bool WF32, bool WB16>
__global__ __launch_bounds__(256) void mgemm(
    const bf16* __restrict__ A, const bf16* __restrict__ Bt,
    const float* __restrict__ bias, const float* __restrict__ res,
    float* __restrict__ Cf, bf16* __restrict__ Cb, int M, int N, int K)
{
    __shared__ __align__(16) bf16 As[128 * 32];
    __shared__ __align__(16) bf16 Bs[128 * 32];
    const int tid  = threadIdx.x;
    const int m0   = blockIdx.y * 128;
    const int n0   = blockIdx.x * 128;
    const int wave = tid >> 6, lane = tid & 63;
    const int wm = (wave >> 1) * 64, wn = (wave & 1) * 64;

    f32x4 acc[4][4] = {};

    const int srow = tid >> 2;
    const int scol = (tid & 3) * 8;
    const bf16* Ag = A  + (size_t)(m0 + srow) * K + scol;
    const bf16* Bg = Bt + (size_t)(n0 + srow) * K + scol;
    bf16* Al = &As[tid * 8];
    bf16* Bl = &Bs[tid * 8];
    const size_t half = (size_t)64 * K;

    const int fr = lane & 15;
    const int kq = (lane >> 4) * 8;
    const bf16* pa = &As[(wm + fr) * 32 + kq];
    const bf16* pb = &Bs[(wn + fr) * 32 + kq];

    for (int k0 = 0; k0 < K; k0 += 32) {
        gld16(Ag + k0,        Al);
        gld16(Ag + k0 + half, Al + 64 * 32);
        gld16(Bg + k0,        Bl);
        gld16(Bg + k0 + half, Bl + 64 * 32);
        __syncthreads();

        bf16x8 af[4], bfr[4];
        #pragma unroll
        for (int i = 0; i < 4; ++i) af[i]  = *(const bf16x8*)(pa + i * 16 * 32);
        #pragma unroll
        for (int j = 0; j < 4; ++j) bfr[j] = *(const bf16x8*)(pb + j * 16 * 32);
        #pragma unroll
        for (int i = 0; i < 4; ++i)
            #pragma unroll
            for (int j = 0; j < 4; ++j)
                acc[i][j] = __builtin_amdgcn_mfma_f32_16x16x32_bf16(
                    af[i], bfr[j], acc[i][j], 0, 0, 0);
        __syncthreads();
    }

    const int colb = n0 + wn + (lane & 15);
    const int rowb = m0 + wm + (lane >> 4) * 4;
    #pragma unroll
    for (int i = 0; i < 4; ++i) {
        #pragma unroll
        for (int j = 0; j < 4; ++j) {
            const int c = colb + j * 16;
            const float bj = bias[c];
            #pragma unroll
            for (int r = 0; r < 4; ++r) {
                const int m = rowb + i * 16 + r;
                float v = acc[i][j][r] + bj;
                if (OP == OP_GELU) v = gelu_tanh(v);
                if (OP == OP_RES)  v += res[(size_t)m * N + c];
                if (WF32) Cf[(size_t)m * N + c] = v;
                if (WB16) Cb[(size_t)m * N + c] = (bf16)v;
            }
        }
    }
}

// ---------------------------------------------------------------------------
// bf16 MFMA GEMM, 64x128 tile: doubles grid for occupancy-starved shapes.
// 4 waves as 2(m)x2(n); each wave 32m x 64n (acc 2x4). LDS 12 KB.
// ---------------------------------------------------------------------------
template <int OP, bool WF32, bool WB16>
__global__ __launch_bounds__(256) void mgemm64(
    const bf16* __restrict__ A, const bf16* __restrict__ Bt,
    const float* __restrict__ bias, const float* __restrict__ res,
    float* __restrict__ Cf, bf16* __restrict__ Cb, int M, int N, int K)
{
    __shared__ __align__(16) bf16 As[64 * 32];
    __shared__ __align__(16) bf16 Bs[128 * 32];
    const int tid  = threadIdx.x;
    const int m0   = blockIdx.y * 64;
    const int n0   = blockIdx.x * 128;
    const int wave = tid >> 6, lane = tid & 63;
    const int wm = (wave >> 1) * 32, wn = (wave & 1) * 64;

    f32x4 acc[2][4] = {};

    const int srow = tid >> 2;
    const int scol = (tid & 3) * 8;
    const bf16* Ag = A  + (size_t)(m0 + srow) * K + scol;
    const bf16* Bg = Bt + (size_t)(n0 + srow) * K + scol;
    bf16* Al = &As[tid * 8];
    bf16* Bl = &Bs[tid * 8];
    const size_t half = (size_t)64 * K;

    const int fr = lane & 15;
    const int kq = (lane >> 4) * 8;
    const bf16* pa = &As[(wm + fr) * 32 + kq];
    const bf16* pb = &Bs[(wn + fr) * 32 + kq];

    for (int k0 = 0; k0 < K; k0 += 32) {
        gld16(Ag + k0,        Al);
        gld16(Bg + k0,        Bl);
        gld16(Bg + k0 + half, Bl + 64 * 32);
        __syncthreads();

        bf16x8 af[2], bfr[4];
        #pragma unroll
        for (int i = 0; i < 2; ++i) af[i]  = *(const bf16x8*)(pa + i * 16 * 32);
        #pragma unroll
        for (int j = 0; j < 4; ++j) bfr[j] = *(const bf16x8*)(pb + j * 16 * 32);
        #pragma unroll
        for (int i = 0; i < 2; ++i)
            #pragma unroll
            for (int j = 0; j < 4; ++j)
                acc[i][j] = __builtin_amdgcn_mfma_f32_16x16x32_bf16(
                    af[i], bfr[j], acc[i][j], 0, 0, 0);
        __syncthreads();
    }

    const int colb = n0 + wn + (lane & 15);
    const int rowb = m0 + wm + (lane >> 4) * 4;
    #pragma unroll
    for (int i = 0; i < 2; ++i) {
        #pragma unroll
        for (int j = 0; j < 4; ++j) {
            const int c = colb + j * 16;
            const float bj = bias[c];
            #pragma unroll
            for (int r = 0; r < 4; ++r) {
                const int m = rowb + i * 16 + r;
                float v = acc[i][j][r] + bj;
                if (OP == OP_GELU) v = gelu_tanh(v);
                if (OP == OP_RES)  v += res[(size_t)m * N + c];
                if (WF32) Cf[(size_t)m * N + c] = v;
                if (WB16) Cb[(size_t)m * N + c] = (bf16)v;
            }
        }
    }
}

// ---------------------------------------------------------------------------
// All 9 weight transposes (fp32 KxN -> bf16 NxK) in ONE launch.
// ---------------------------------------------------------------------------
struct TDesc { const float* src; bf16* dst; int K; int N; int tile0; };
struct TDescs { TDesc d[9]; };

__global__ __launch_bounds__(256) void transpose_all(TDescs td)
{
    __shared__ float t[32][33];
    const int blk = blockIdx.x;
    int i = 0;
    #pragma unroll
    for (int j = 1; j < 9; ++j) if (blk >= td.d[j].tile0) i = j;
    const float* src = td.d[i].src;
    bf16* dst = td.d[i].dst;
    const int K = td.d[i].K, N = td.d[i].N;
    const int local = blk - td.d[i].tile0;
    const int ntx = N >> 5;
    const int bx = local % ntx, by = local / ntx;
    const int x = threadIdx.x & 31, y = threadIdx.x >> 5;
    #pragma unroll
    for (int p = 0; p < 32; p += 8)
        t[y + p][x] = src[(size_t)(by * 32 + y + p) * N + bx * 32 + x];
    __syncthreads();
    #pragma unroll
    for (int p = 0; p < 32; p += 8)
        dst[(size_t)(bx * 32 + y + p) * K + by * 32 + x] = (bf16)t[x][y + p];
}

// fp32 -> bf16 elementwise
__global__ __launch_bounds__(256) void cvt_kernel(
    const float* __restrict__ in, bf16* __restrict__ out, int n4)
{
    int i = blockIdx.x * 256 + threadIdx.x;
    if (i >= n4) return;
    float4 v = ((const float4*)in)[i];
    out[4 * i + 0] = (bf16)v.x;
    out[4 * i + 1] = (bf16)v.y;
    out[4 * i + 2] = (bf16)v.z;
    out[4 * i + 3] = (bf16)v.w;
}

// kv = x @ Wm + bm  (K=4), bf16 out.
__global__ __launch_bounds__(256) void kv_kernel(
    const float* __restrict__ x, const float* __restrict__ Wm,
    const float* __restrict__ bm, bf16* __restrict__ kv)
{
    int idx = blockIdx.x * 256 + threadIdx.x;
    int r = idx >> 10, n = idx & 1023;
    float4 xv = *(const float4*)(x + (size_t)r * 4);
    float v = bm[n] + xv.x * Wm[n] + xv.y * Wm[1024 + n]
                    + xv.z * Wm[2048 + n] + xv.w * Wm[3072 + n];
    kv[idx] = (bf16)v;
}

// 3D RoPE: bf16 in (row stride istr, col offset icoff) -> bf16 out (rows x 512).
__global__ __launch_bounds__(256) void rope_b_kernel(
    const bf16* __restrict__ in, bf16* __restrict__ out,
    int tok, int gdiv, int wdiv, int total, float sc, int istr, int icoff)
{
    int idx = blockIdx.x * 256 + threadIdx.x;
    if (idx >= total) return;
    int row = idx >> 7;
    int r2 = idx & 127;
    int h = r2 >> 5;
    int j2 = r2 & 31;
    int j = 2 * j2;
    int n = row % tok;
    int t = n / gdiv;
    int g = n % gdiv;
    int gh = g / wdiv;
    int gw = g % wdiv;
    float pa = (j < 22) ? (float)t : (j < 43) ? (float)gh : (float)gw;
    int j1 = j + 1;
    float pb = (j1 < 22) ? (float)t : (j1 < 43) ? (float)gh : (float)gw;
    float fra = pa * exp2f(-(float)j  * 0.20762050593045954f);
    float frb = pb * exp2f(-(float)j1 * 0.20762050593045954f);
    float ca = cosf(fra), sa = sinf(fra);
    float cb = cosf(frb), sb = sinf(frb);
    size_t ibase = (size_t)row * istr + icoff + (size_t)h * 128 + j;
    size_t obase = (size_t)row * 512 + (size_t)h * 128 + j;
    union { u32 w; bf16 e[2]; } ua, ub;
    ua.w = *(const u32*)(in + ibase);
    ub.w = *(const u32*)(in + ibase + 64);
    float x1a = (float)ua.e[0], x1b = (float)ua.e[1];
    float x2a = (float)ub.e[0], x2b = (float)ub.e[1];
    *(u32*)(out + obase)      = pack_bf16((x1a * ca - x2a * sa) * sc,
                                          (x1b * cb - x2b * sb) * sc);
    *(u32*)(out + obase + 64) = pack_bf16((x2a * ca + x1a * sa) * sc,
                                          (x2b * cb + x1b * sb) * sc);
}

// Coalesced V transpose: kv16[t][512 + h*128 + d] -> Vt[b][h][d][2048]
__global__ __launch_bounds__(256) void vt_tiled(
    const bf16* __restrict__ kv16, bf16* __restrict__ vt)
{
    __shared__ bf16 t[64][72];
    const int tt = blockIdx.x * 64;
    const int d0 = blockIdx.y * 64;
    const int bh = blockIdx.z;
    const int b = bh >> 2, h = bh & 3;
    const int rr = threadIdx.x >> 4;
    const int cc = (threadIdx.x & 15) * 4;
    #pragma unroll
    for (int p = 0; p < 4; ++p) {
        int r = rr + p * 16;
        *(bf16x4*)&t[r][cc] = *(const bf16x4*)
            (kv16 + (size_t)(b * ROWS_K + tt + r) * 1024 + 512 + h * 128 + d0 + cc);
    }
    __syncthreads();
    #pragma unroll
    for (int p = 0; p < 4; ++p) {
        int r = rr + p * 16;   // d-local
        bf16x4 v;
        v[0] = t[cc + 0][r]; v[1] = t[cc + 1][r];
        v[2] = t[cc + 2][r]; v[3] = t[cc + 3][r];
        *(bf16x4*)(vt + (size_t)bh * HD * ROWS_K + (size_t)(d0 + r) * ROWS_K + tt + cc) = v;
    }
}

// LayerNorm in-place on (rows x 512) + bf16 copy.
__global__ __launch_bounds__(256) void ln_kernel(
    float* __restrict__ xb, const float* __restrict__ g,
    const float* __restrict__ be, bf16* __restrict__ out16)
{
    int wave = threadIdx.x >> 6, lane = threadIdx.x & 63;
    size_t row = (size_t)blockIdx.x * 4 + wave;
    float* xp = xb + row * 512;
    float4 a = ((const float4*)xp)[lane];
    float4 b = ((const float4*)xp)[lane + 64];
    float s  = a.x + a.y + a.z + a.w + b.x + b.y + b.z + b.w;
    float sq = a.x*a.x + a.y*a.y + a.z*a.z + a.w*a.w
             + b.x*b.x + b.y*b.y + b.z*b.z + b.w*b.w;
    #pragma unroll
    for (int off = 32; off; off >>= 1) {
        s  += __shfl_xor(s, off);
        sq += __shfl_xor(sq, off);
    }
    float mean = s * (1.0f / 512.0f);
    float var  = sq * (1.0f / 512.0f) - mean * mean;
    float rstd = rsqrtf(var + 1e-5f);
    float4 gv1 = ((const float4*)g)[lane],  gv2 = ((const float4*)g)[lane + 64];
    float4 bv1 = ((const float4*)be)[lane], bv2 = ((const float4*)be)[lane + 64];
    a.x = (a.x - mean) * rstd * gv1.x + bv1.x;
    a.y = (a.y - mean) * rstd * gv1.y + bv1.y;
    a.z = (a.z - mean) * rstd * gv1.z + bv1.z;
    a.w = (a.w - mean) * rstd * gv1.w + bv1.w;
    b.x = (b.x - mean) * rstd * gv2.x + bv2.x;
    b.y = (b.y - mean) * rstd * gv2.y + bv2.y;
    b.z = (b.z - mean) * rstd * gv2.z + bv2.z;
    b.w = (b.w - mean) * rstd * gv2.w + bv2.w;
    ((float4*)xp)[lane]      = a;
    ((float4*)xp)[lane + 64] = b;
    bf16* op = out16 + row * 512;
    *(u32*)(op + lane * 4)       = pack_bf16(a.x, a.y);
    *(u32*)(op + lane * 4 + 2)   = pack_bf16(a.z, a.w);
    *(u32*)(op + 256 + lane * 4)     = pack_bf16(b.x, b.y);
    *(u32*)(op + 256 + lane * 4 + 2) = pack_bf16(b.z, b.w);
}

// ---------------------------------------------------------------------------
// MFMA flash attention (bf16, fp32 accum) — unchanged from round 5.
// ---------------------------------------------------------------------------
__global__ __launch_bounds__(256, 2) void mattn_kernel(
    const bf16* __restrict__ qs, const bf16* __restrict__ ks,
    const bf16* __restrict__ vt, bf16* __restrict__ outb)
{
    __shared__ __align__(16) char smem[35840];
    bf16* Ksh = (bf16*)smem;            // [64][136]
    bf16* Vsh = (bf16*)(smem + 17408);  // [128][72]

    const int tid = threadIdx.x;
    const int wave = tid >> 6, lane = tid & 63;
    const int quad = lane >> 4, c = lane & 15;
    const int bid = blockIdx.x;
    const int qt = bid % 49;
    const int h  = (bid / 49) & 3;
    const int b  = bid / 196;

    const int q0 = qt * 128 + wave * 32;
    const bf16* qg = qs + (size_t)(b * ROWS_Q + q0) * HID + h * HD;
    const bf16* kg = ks + (size_t)(b * ROWS_K) * HID + h * HD;
    const bf16* vg = vt + (size_t)(b * NH + h) * HD * ROWS_K;

    bf16x8 qf[2][4];
    #pragma unroll
    for (int n = 0; n < 2; ++n)
        #pragma unroll
        for (int s = 0; s < 4; ++s)
            qf[n][s] = *(const bf16x8*)(qg + (size_t)(n * 16 + c) * HID + s * 32 + quad * 8);

    f32x4 o[8][2] = {};
    float m_i[2] = {-1e30f, -1e30f}, l_i[2] = {0.0f, 0.0f};

    const int st_t = tid >> 2;
    const int st_d = (tid & 3) * 32;
    const int sv_d = tid >> 1;
    const int sv_t = (tid & 1) * 32;

    for (int kt = 0; kt < 32; ++kt) {
        __syncthreads();
        {
            const bf16* src = kg + (size_t)(kt * 64 + st_t) * HID + st_d;
            bf16* dst = Ksh + st_t * 136 + st_d;
            #pragma unroll
            for (int i = 0; i < 4; ++i)
                *(bf16x8*)(dst + i * 8) = *(const bf16x8*)(src + i * 8);
        }
        {
            const bf16* src = vg + (size_t)sv_d * ROWS_K + kt * 64 + sv_t;
            bf16* dst = Vsh + sv_d * 72 + sv_t;
            #pragma unroll
            for (int i = 0; i < 4; ++i)
                *(bf16x8*)(dst + i * 8) = *(const bf16x8*)(src + i * 8);
        }
        __syncthreads();

        f32x4 s[4][2] = {};
        #pragma unroll
        for (int ksi = 0; ksi < 4; ++ksi) {
            bf16x8 kf[4];
            #pragma unroll
            for (int mi = 0; mi < 4; ++mi)
                kf[mi] = *(const bf16x8*)(Ksh + (mi * 16 + c) * 136 + ksi * 32 + quad * 8);
            #pragma unroll
            for (int mi = 0; mi < 4; ++mi)
                #pragma unroll
                for (int n = 0; n < 2; ++n)
                    s[mi][n] = __builtin_amdgcn_mfma_f32_16x16x32_bf16(
                        kf[mi], qf[n][ksi], s[mi][n], 0, 0, 0);
        }

        float alpha[2];
        #pragma unroll
        for (int n = 0; n < 2; ++n) {
            float mx = -1e30f;
            #pragma unroll
            for (int mi = 0; mi < 4; ++mi)
                #pragma unroll
                for (int r = 0; r < 4; ++r) mx = fmaxf(mx, s[mi][n][r]);
            mx = fmaxf(mx, __shfl_xor(mx, 16));
            mx = fmaxf(mx, __shfl_xor(mx, 32));
            float mn = fmaxf(m_i[n], mx);
            alpha[n] = __expf(m_i[n] - mn);
            m_i[n] = mn;
            float sm = 0.0f;
            #pragma unroll
            for (int mi = 0; mi < 4; ++mi)
                #pragma unroll
                for (int r = 0; r < 4; ++r) {
                    float p = __expf(s[mi][n][r] - mn);
                    s[mi][n][r] = p;
                    sm += p;
                }
            sm += __shfl_xor(sm, 16);
            sm += __shfl_xor(sm, 32);
            l_i[n] = l_i[n] * alpha[n] + sm;
            #pragma unroll
            for (int md = 0; md < 8; ++md) {
                o[md][n][0] *= alpha[n]; o[md][n][1] *= alpha[n];
                o[md][n][2] *= alpha[n]; o[md][n][3] *= alpha[n];
            }
        }

        u32 pk[4][2][2];
        #pragma unroll
        for (int mi = 0; mi < 4; ++mi)
            #pragma unroll
            for (int n = 0; n < 2; ++n) {
                pk[mi][n][0] = pack_bf16(s[mi][n][0], s[mi][n][1]);
                pk[mi][n][1] = pack_bf16(s[mi][n][2], s[mi][n][3]);
            }
        bf16x8 pf[2][2];
        #pragma unroll
        for (int kst = 0; kst < 2; ++kst)
            #pragma unroll
            for (int n = 0; n < 2; ++n) {
                union { bf16x8 v8; u32 d[4]; } u;
                #pragma unroll
                for (int dw = 0; dw < 4; ++dw) {
                    int srcl = ((quad & 1) * 2 + (dw >> 1)) * 16 + c;
                    u32 lo = (u32)__shfl((int)pk[2 * kst][n][dw & 1], srcl);
                    u32 hi = (u32)__shfl((int)pk[2 * kst + 1][n][dw & 1], srcl);
                    u.d[dw] = (quad >= 2) ? hi : lo;
                }
                pf[kst][n] = u.v8;
            }

        #pragma unroll
        for (int kst = 0; kst < 2; ++kst)
            #pragma unroll
            for (int md = 0; md < 8; ++md) {
                bf16x8 vf = *(const bf16x8*)(Vsh + (md * 16 + c) * 72 + kst * 32 + quad * 8);
                #pragma unroll
                for (int n = 0; n < 2; ++n)
                    o[md][n] = __builtin_amdgcn_mfma_f32_16x16x32_bf16(
                        vf, pf[kst][n], o[md][n], 0, 0, 0);
            }
    }

    __syncthreads();
    bf16* Osh = (bf16*)smem + wave * (32 * 136);
    float inv[2] = {1.0f / l_i[0], 1.0f / l_i[1]};
    #pragma unroll
    for (int md = 0; md < 8; ++md)
        #pragma unroll
        for (int n = 0; n < 2; ++n)
            #pragma unroll
            for (int hh = 0; hh < 2; ++hh) {
                u32 w = pack_bf16(o[md][n][2 * hh] * inv[n], o[md][n][2 * hh + 1] * inv[n]);
                int d = md * 16 + quad * 4 + 2 * hh;
                int qq = n * 16 + c;
                *(u32*)(Osh + qq * 136 + d) = w;
            }
    __syncthreads();
    bf16* og = outb + (size_t)(b * ROWS_Q + q0) * HID + h * HD;
    #pragma unroll
    for (int i = 0; i < 8; ++i) {
        int idx = i * 64 + lane;
        int qq = idx >> 4;
        int ch = idx & 15;
        bf16x8 vv = *(const bf16x8*)(Osh + qq * 136 + ch * 8);
        *(bf16x8*)(og + (size_t)qq * HID + ch * 8) = vv;
    }
}

extern "C" void kernel_launch(void* const* d_in, const int* in_sizes, int n_in,
                              void* d_out, int out_size, void* d_ws, size_t ws_size,
                              hipStream_t stream)
{
    const float* x     = (const float*)d_in[0];
    const float* slow  = (const float*)d_in[1];
    const float* Wq_in = (const float*)d_in[3];
    const float* bq_in = (const float*)d_in[4];
    const float* Wm    = (const float*)d_in[5];
    const float* bm    = (const float*)d_in[6];
    const float* Wq    = (const float*)d_in[7];
    const float* bq    = (const float*)d_in[8];
    const float* Wk    = (const float*)d_in[9];
    const float* bk    = (const float*)d_in[10];
    const float* Wv    = (const float*)d_in[11];
    const float* bv    = (const float*)d_in[12];
    const float* Wo    = (const float*)d_in[13];
    const float* bo    = (const float*)d_in[14];
    const float* g1    = (const float*)d_in[15];
    const float* be1   = (const float*)d_in[16];
    const float* W1    = (const float*)d_in[17];
    const float* b1    = (const float*)d_in[18];
    const float* W2    = (const float*)d_in[19];
    const float* b2    = (const float*)d_in[20];
    const float* g2    = (const float*)d_in[21];
    const float* be2   = (const float*)d_in[22];
    const float* M1    = (const float*)d_in[23];
    const float* bm1   = (const float*)d_in[24];
    const float* M2    = (const float*)d_in[25];
    const float* bm2   = (const float*)d_in[26];
    float* out = (float*)d_out;

    // ---- workspace layout ----
    float* q_in_f = (float*)d_ws;                         // MQ*512 f32
    float* ob     = q_in_f + (size_t)MQ * HID;            // MQ*512 f32
    float* bkv    = ob + (size_t)MQ * HID;                // 1024 f32
    bf16* shared_b = (bf16*)(bkv + 1024);                 // MQ*1024 (slow_b/attn_b/ff1_b/m1_b)
    bf16* q_in_b = shared_b + (size_t)MQ * FF;            // MQ*512
    bf16* kv_b   = q_in_b + (size_t)MQ * HID;             // MK*1024
    bf16* h_b    = kv_b + (size_t)MK * EMB;               // MQ*512
    bf16* q16    = h_b + (size_t)MQ * HID;                // MQ*512
    bf16* kv16   = q16 + (size_t)MQ * HID;                // MK*1024 (k|v fused)
    bf16* qbt    = kv16 + (size_t)MK * EMB;               // MQ*512
    bf16* kbt    = qbt + (size_t)MQ * HID;                // MK*512
    bf16* Vt     = kbt + (size_t)MK * HID;                // 8*128*2048
    bf16* Wq_in_t = Vt + (size_t)8 * HD * ROWS_K;         // 512*896
    bf16* Wq_t  = Wq_in_t + 512 * 896;                    // 512*512
    bf16* kvw_t = Wq_t + 512 * 512;                       // 1024*1024 (Wk_t | Wv_t)
    bf16* Wo_t  = kvw_t + 1024 * 1024;                    // 512*512
    bf16* W1_t  = Wo_t + 512 * 512;                       // 1024*512
    bf16* W2_t  = W1_t + 1024 * 512;                      // 512*1024
    bf16* M1_t  = W2_t + 512 * 1024;                      // 1024*512
    bf16* M2_t  = M1_t + 1024 * 512;                      // 896*1024
    bf16* slow_b = shared_b;
    bf16* attn_b = shared_b;
    bf16* ff1_b  = shared_b;
    bf16* m1_b   = shared_b;

    dim3 blk(256);

    // ---- all weight transposes in one launch ----
    TDescs td;
    int t0 = 0;
    auto set = [&](int i, const float* s, bf16* d, int K, int N) {
        td.d[i] = {s, d, K, N, t0};
        t0 += (N / 32) * (K / 32);
    };
    set(0, Wq_in, Wq_in_t, 896, 512);
    set(1, Wq,    Wq_t,    512, 512);
    set(2, Wk,    kvw_t,              1024, 512);
    set(3, Wv,    kvw_t + 512 * 1024, 1024, 512);
    set(4, Wo,    Wo_t,    512, 512);
    set(5, W1,    W1_t,    512, 1024);
    set(6, W2,    W2_t,    1024, 512);
    set(7, M1,    M1_t,    512, 1024);
    set(8, M2,    M2_t,    1024, 896);
    transpose_all<<<t0, blk, 0, stream>>>(td);

    // bias concat for fused KV GEMM
    hipMemcpyAsync(bkv,       bk, 512 * sizeof(float), hipMemcpyDeviceToDevice, stream);
    hipMemcpyAsync(bkv + 512, bv, 512 * sizeof(float), hipMemcpyDeviceToDevice, stream);

    cvt_kernel<<<(MQ * DQ / 4 + 255) / 256, blk, 0, stream>>>(slow, slow_b, MQ * DQ / 4);
    kv_kernel<<<(MK * EMB) / 256, blk, 0, stream>>>(x, Wm, bm, kv_b);

    // q_in = slow @ Wq_in + bq_in -> fp32 (residual) + bf16   grid 4x196
    mgemm64<OP_BIAS, true, true><<<dim3(4, 196), blk, 0, stream>>>(
        slow_b, Wq_in_t, bq_in, nullptr, q_in_f, q_in_b, MQ, HID, DQ);
    // q projection -> bf16   grid 4x196
    mgemm64<OP_BIAS, false, true><<<dim3(4, 196), blk, 0, stream>>>(
        q_in_b, Wq_t, bq, nullptr, nullptr, q16, MQ, HID, HID);
    // fused k|v projection -> kv16 (MK x 1024)   grid 8x64
    mgemm64<OP_BIAS, false, true><<<dim3(8, 64), blk, 0, stream>>>(
        kv_b, kvw_t, bkv, nullptr, nullptr, kv16, MK, 1024, EMB);
    // RoPE (q pre-scaled by 1/sqrt(128)); k read from fused kv16
    rope_b_kernel<<<(MQ * 128 + 255) / 256, blk, 0, stream>>>(
        q16, qbt, ROWS_Q, 196, 14, MQ * 128, 0.08838834764831843f, 512, 0);
    rope_b_kernel<<<(MK * 128 + 255) / 256, blk, 0, stream>>>(
        kv16, kbt, ROWS_K, 64, 8, MK * 128, 1.0f, 1024, 0);
    // V transpose (coalesced)
    vt_tiled<<<dim3(32, 2, 8), blk, 0, stream>>>(kv16, Vt);
    // MFMA flash attention -> attn_b (bf16)
    mattn_kernel<<<dim3(392), blk, 0, stream>>>(qbt, kbt, Vt, attn_b);
    // pre_ln = attn @ Wo + bo + q_in   grid 4x196
    mgemm64<OP_RES, true, false><<<dim3(4, 196), blk, 0, stream>>>(
        attn_b, Wo_t, bo, q_in_f, ob, nullptr, MQ, HID, HID);
    ln_kernel<<<MQ / 4, blk, 0, stream>>>(ob, g1, be1, h_b);
    // ff1 = gelu(h @ W1 + b1)   grid 8x98 (128-tile)
    mgemm<OP_GELU, false, true><<<dim3(8, 98), blk, 0, stream>>>(
        h_b, W1_t, b1, nullptr, nullptr, ff1_b, MQ, FF, HID);
    // pre2 = ff1 @ W2 + b2 + h   grid 4x196
    mgemm64<OP_RES, true, false><<<dim3(4, 196), blk, 0, stream>>>(
        ff1_b, W2_t, b2, ob, q_in_f, nullptr, MQ, HID, FF);
    ln_kernel<<<MQ / 4, blk, 0, stream>>>(q_in_f, g2, be2, h_b);
    // m1 = gelu(h2 @ M1 + bm1)   grid 8x98
    mgemm<OP_GELU, false, true><<<dim3(8, 98), blk, 0, stream>>>(
        h_b, M1_t, bm1, nullptr, nullptr, m1_b, MQ, 2 * HID, HID);
    // out = m1 @ M2 + bm2   grid 7x98
    mgemm<OP_BIAS, true, false><<<dim3(7, 98), blk, 0, stream>>>(
        m1_b, M2_t, bm2, nullptr, out, nullptr, MQ, OUTD, 2 * HID);
}